// Round 18
// baseline (1715.225 us; speedup 1.0000x reference)
//
#include <hip/hip_runtime.h>

// ---------------------------------------------------------------------------
// MemMambaBlock on MI355X.  B=4 T=2048 D=1024 D_INNER=2048 D_STATE=128
// NHEADS=32 HEADDIM=64 D_CONV=4 POOL=64 SUMDIM=256 d_in_proj=4384
// Scan v10 (this round): NC=8 chunks (CL=256) -> 4096 blocks, ~13 resident
// blocks/CU (R17: grid-limited at 8, occupancy 20%, VALUBusy 44%).  Step
// machinery / lane layout / DMA ring / counted-vmcnt invariant unchanged.
// Boundary prefix generalized to 7 chunks; hend (29.4MB) lives in the DEAD
// d_out y-region (fully overwritten by out_proj at step 6) -> ws shrinks.
// GEMM v9 (kept): fp16 2-plane split + per-pass fragments + chunk swizzle +
// 2-phase double-buffered K-loop, (256,2).  f64 conv/norms/score head.
// ---------------------------------------------------------------------------

using u16 = unsigned short;
using f16x8 = __attribute__((ext_vector_type(8))) _Float16;
using f32x4  = __attribute__((ext_vector_type(4))) float;

#define DEV __device__ __forceinline__

#define GLOAD4(g, l)  __builtin_amdgcn_global_load_lds((const __attribute__((address_space(1))) void*)(g), (__attribute__((address_space(3))) void*)(l), 4, 0, 0)
#define GLOAD16(g, l) __builtin_amdgcn_global_load_lds((const __attribute__((address_space(1))) void*)(g), (__attribute__((address_space(3))) void*)(l), 16, 0, 0)
#define VMWAIT(N) asm volatile("s_waitcnt vmcnt(" #N ")" ::: "memory")

static constexpr int Bb = 4, T = 2048, D = 1024;
static constexpr int DIN = 2048, DST = 128, NH = 32;
static constexpr int DPROJ = 4384;          // 2*DIN + 2*DST + NH
static constexpr int CCH = 2304;            // DIN + 2*DST (conv channels)
static constexpr int ROWS = Bb * T;         // 8192
static constexpr int NC = 8, CL = 256;      // chunks x chunk length
static constexpr float RSC = 4096.f, RSCI = 1.f / 4096.f;

DEV u16 f2h_bits(float f) { union { _Float16 h; u16 u; } v; v.h = (_Float16)f; return v.u; }
DEV float h2f(u16 u) { union { _Float16 h; u16 u; } v; v.u = u; return (float)v.h; }
DEV double sigd(double x) { return 1.0 / (1.0 + exp(-x)); }
DEV int swz(int c) { return c ^ ((c >> 3) & 3); }   // involution, row-preserving

__global__ void diag_kernel(float* o, float v) { if (threadIdx.x == 0) o[0] = v; }
__global__ void zerod_kernel(double* p, int n) { if ((int)threadIdx.x < n) p[threadIdx.x] = 0.0; }

// ------------------------------------- 2-plane fp16 split (scaled residual)
__global__ void split2_kernel(const float* __restrict__ in, u16* __restrict__ out, long n) {
    long i = (long)blockIdx.x * 256 + threadIdx.x;
    if (i >= n) return;
    float v = in[i];
    u16 h = f2h_bits(v);
    float r1 = (v - h2f(h)) * RSC;
    out[i] = h;
    out[n + i] = f2h_bits(r1);
}

// ------------------------------------------- rmsnorm(x) -> 2 fp16 planes
__global__ __launch_bounds__(256) void rms_x_kernel(const float* __restrict__ x, const float* __restrict__ w,
                                                    u16* __restrict__ up, long pstride) {
    long row = blockIdx.x; int tid = threadIdx.x;
    const float* xr = x + row * D;
    float4 xv = *(const float4*)(xr + tid * 4);
    double ss = (double)xv.x * xv.x + (double)xv.y * xv.y + (double)xv.z * xv.z + (double)xv.w * xv.w;
    for (int off = 1; off < 64; off <<= 1) ss += __shfl_xor(ss, off);
    __shared__ double tmp[4];
    if ((tid & 63) == 0) tmp[tid >> 6] = ss;
    __syncthreads();
    double tot = tmp[0] + tmp[1] + tmp[2] + tmp[3];
    double scale = 1.0 / sqrt(tot / (double)D + 1e-4);
    float4 wv = *(const float4*)(w + tid * 4);
    long base = row * D + tid * 4;
    float vals[4];
    vals[0] = (float)((double)xv.x * scale * (double)wv.x);
    vals[1] = (float)((double)xv.y * scale * (double)wv.y);
    vals[2] = (float)((double)xv.z * scale * (double)wv.z);
    vals[3] = (float)((double)xv.w * scale * (double)wv.w);
#pragma unroll
    for (int j = 0; j < 4; j++) {
        float f = vals[j];
        u16 h = f2h_bits(f);
        up[base + j] = h;
        up[pstride + base + j] = f2h_bits((f - h2f(h)) * RSC);
    }
}

// ----------------------------------------------------------------- GEMM
// Row-major tiles [128][32] u16 viewed as 512 16B chunks (c = row*4 + q);
// physical placement swizzled by s(c) = c ^ ((c>>3)&3).
template <int NP>
DEV void stage_one(u16* s0, u16* s1, const float* __restrict__ src, long ld,
                   int row0, int lastrow, int k0, int tid) {
    int r = tid >> 1, cb = (tid & 1) * 2;       // chunk-col base (0 or 2)
    long rg = row0 + r; if (rg > lastrow) rg = lastrow;
    const float* p = src + rg * ld + k0 + cb * 8;
    u16 h16[16], l16[16];
#pragma unroll
    for (int q = 0; q < 4; q++) {
        float4 v4 = *(const float4*)(p + q * 4);
        float vv[4] = { v4.x, v4.y, v4.z, v4.w };
#pragma unroll
        for (int j = 0; j < 4; j++) {
            float xv = vv[j];
            u16 h = f2h_bits(xv);
            h16[q * 4 + j] = h;
            if constexpr (NP == 2) l16[q * 4 + j] = f2h_bits((xv - h2f(h)) * RSC);
        }
    }
    int o0 = swz(r * 4 + cb) * 8, o1 = swz(r * 4 + cb + 1) * 8;
    *(uint4*)(s0 + o0) = *(const uint4*)(h16);
    *(uint4*)(s0 + o1) = *(const uint4*)(h16 + 8);
    if constexpr (NP == 2) {
        *(uint4*)(s1 + o0) = *(const uint4*)(l16);
        *(uint4*)(s1 + o1) = *(const uint4*)(l16 + 8);
    }
}

// DMA staging: LDS chunk s (linear dest) holds global chunk swz(s); wave
// quarter still covers the same contiguous 1KB global span (coalesced).
DEV void stage_pre_dma(u16* dst, const u16* __restrict__ src, long ld,
                       int row0, int lastrow, int k0, int wid, int lane) {
#pragma unroll
    for (int j = 0; j < 2; j++) {
        int s = wid * 128 + j * 64 + lane;
        int g = swz(s);
        int r = g >> 2, cs = g & 3;
        long rg = row0 + r; if (rg > lastrow) rg = lastrow;
        const u16* gp = src + rg * ld + k0 + cs * 8;
        GLOAD16(gp, dst + (wid * 128 + j * 64) * 8);
    }
}

// stage one K-tile (all planes, A+B) into buffer base bb
#define STAGE_TILE(bb, k0_) do { \
    u16* As0_ = (bb); \
    u16* As1_ = (bb) + 4096; \
    u16* Bs0_ = (bb) + NP * 4096; \
    u16* Bs1_ = (bb) + NP * 4096 + 4096; \
    if constexpr (BP) { \
        stage_pre_dma(Bs0_, Bp, K, tN, N - 1, (k0_), wid, lane); \
        if constexpr (NP == 2) stage_pre_dma(Bs1_, Bp + bstride, K, tN, N - 1, (k0_), wid, lane); \
    } \
    if constexpr (AP) { \
        stage_pre_dma(As0_, Ap, K, tM, M - 1, (k0_), wid, lane); \
        if constexpr (NP == 2) stage_pre_dma(As1_, Ap + astride, K, tM, M - 1, (k0_), wid, lane); \
    } else { \
        stage_one<NP>(As0_, NP == 2 ? As1_ : nullptr, A, lda, tM, M - 1, (k0_), tid); \
    } \
    if constexpr (!BP) { \
        stage_one<NP>(Bs0_, NP == 2 ? Bs1_ : nullptr, B, ldb, tN, N - 1, (k0_), tid); \
    } \
} while (0)

template <int NP, int MODE, bool BP, bool AP>
__global__ __launch_bounds__(256, 2) void gemm_f32(
    const float* __restrict__ A, long lda,
    const u16* __restrict__ Ap, size_t astride,
    const float* __restrict__ B, long ldb,
    const u16* __restrict__ Bp, size_t bstride,
    int M, int N, int K,
    float* __restrict__ out0, float* __restrict__ out1,
    const float* __restrict__ aux0, const float* __restrict__ aux1,
    float* __restrict__ dtb, float* __restrict__ dab) {
    __shared__ __align__(16) u16 sm[2 * NP * 2 * 4096];   // double-buffered
    int tid = threadIdx.x, lane = tid & 63, wid = tid >> 6;
    int wr = wid >> 1, wc = wid & 1;
    int nwg = gridDim.x * gridDim.y;
    int wg = blockIdx.y * gridDim.x + blockIdx.x;
    int lin = (wg & 7) * (nwg >> 3) + (wg >> 3);
    int tM = (lin / gridDim.x) * 128, tN = (lin % gridDim.x) * 128;

    f32x4 acc1[4][4], acc2[4][4];
#pragma unroll
    for (int i = 0; i < 4; i++)
#pragma unroll
        for (int j = 0; j < 4; j++) {
            acc1[i][j] = f32x4{0.f, 0.f, 0.f, 0.f};
            if constexpr (NP == 2) acc2[i][j] = f32x4{0.f, 0.f, 0.f, 0.f};
        }

    int rA = wr * 64 + (lane & 15);
    int rB = wc * 64 + (lane & 15);
    int kc = lane >> 4;
    // precomputed swizzled fragment offsets (u16 units)
    int oA[4], oB[4];
#pragma unroll
    for (int i = 0; i < 4; i++) {
        oA[i] = swz((rA + i * 16) * 4 + kc) * 8;
        oB[i] = swz((rB + i * 16) * 4 + kc) * 8;
    }

    int nsteps = K / 32;
    int cur = 0;
    STAGE_TILE(sm, 0);
    __syncthreads();                         // drains prologue DMA + ds_writes
    for (int kt = 0; kt < nsteps; ++kt) {
        u16* cb = sm + cur * (NP * 2 * 4096);
        if (kt + 1 < nsteps) {
            u16* nb = sm + (cur ^ 1) * (NP * 2 * 4096);
            STAGE_TILE(nb, (kt + 1) * 32);   // DMA overlaps this tile's MFMA
        }
        u16* As0 = cb; u16* As1 = cb + 4096;
        u16* Bs0 = cb + NP * 4096; u16* Bs1 = cb + NP * 4096 + 4096;
        f16x8 fa[4], fb[4];
        // pass 1: A0 x B0 -> acc1
#pragma unroll
        for (int i = 0; i < 4; i++) {
            fa[i] = *(const f16x8*)(As0 + oA[i]);
            fb[i] = *(const f16x8*)(Bs0 + oB[i]);
        }
#pragma unroll
        for (int mi = 0; mi < 4; mi++)
#pragma unroll
            for (int ni = 0; ni < 4; ni++)
                acc1[mi][ni] = __builtin_amdgcn_mfma_f32_16x16x32_f16(fa[mi], fb[ni], acc1[mi][ni], 0, 0, 0);
        if constexpr (NP == 2) {
            // pass 2: A0 x B1 -> acc2   (fa still holds A0)
#pragma unroll
            for (int i = 0; i < 4; i++) fb[i] = *(const f16x8*)(Bs1 + oB[i]);
#pragma unroll
            for (int mi = 0; mi < 4; mi++)
#pragma unroll
                for (int ni = 0; ni < 4; ni++)
                    acc2[mi][ni] = __builtin_amdgcn_mfma_f32_16x16x32_f16(fa[mi], fb[ni], acc2[mi][ni], 0, 0, 0);
            // pass 3: A1 x B0 -> acc2
#pragma unroll
            for (int i = 0; i < 4; i++) {
                fa[i] = *(const f16x8*)(As1 + oA[i]);
                fb[i] = *(const f16x8*)(Bs0 + oB[i]);
            }
#pragma unroll
            for (int mi = 0; mi < 4; mi++)
#pragma unroll
                for (int ni = 0; ni < 4; ni++)
                    acc2[mi][ni] = __builtin_amdgcn_mfma_f32_16x16x32_f16(fa[mi], fb[ni], acc2[mi][ni], 0, 0, 0);
        }
        if (kt + 1 < nsteps) {
            __syncthreads();                 // drains next-tile DMA (hidden under MFMA)
            cur ^= 1;
        }
    }
    int laneh = lane >> 4, lanel = lane & 15;
#pragma unroll
    for (int mi = 0; mi < 4; mi++)
#pragma unroll
        for (int ni = 0; ni < 4; ni++) {
            int col = tN + wc * 64 + ni * 16 + lanel;
            if (col >= N) continue;
#pragma unroll
            for (int r = 0; r < 4; r++) {
                long row = tM + wr * 64 + mi * 16 + laneh * 4 + r;
                float v = acc1[mi][ni][r];
                if constexpr (NP == 2) v += acc2[mi][ni][r] * RSCI;
                if constexpr (MODE == 0) {
                    if (col < 2048) out0[row * 2048 + col] = v;
                    else if (col < 4352) out1[row * 2304 + (col - 2048)] = v;
                    else {
                        int h = col - 4352;
                        double xx = (double)v + (double)aux0[h];
                        double sp = (xx > 30.0) ? xx : log1p(exp(xx));
                        double a = -exp((double)aux1[h]);
                        dtb[row * NH + h] = (float)sp;
                        dab[row * NH + h] = (float)exp(sp * a);
                    }
                } else if constexpr (MODE == 1) {
                    out0[row * 256 + col] = fmaxf(v, 0.f);
                } else if constexpr (MODE == 2) {
                    float y = aux0[row * 1024 + col] + v;
                    out0[row * 1024 + col] = y;
                    out1[row * 2048 + col] = y;
                } else if constexpr (MODE == 3) {
                    out0[row * 256 + col] = v;
                } else {
                    double g = sigd((double)v);
                    float retr = aux0[row * 2048 + 1024 + col];
                    out0[row * 1024 + col] += (float)(g * (double)retr * (double)aux1[row >> 11]);
                }
            }
        }
}

// ------------------------------------------------- depthwise causal conv4
__global__ __launch_bounds__(256) void conv_kernel(const float* __restrict__ xin, const float* __restrict__ cw,
                                                   const float* __restrict__ cb, float* __restrict__ xbc) {
    int blk = blockIdx.x;
    int ct = blk % 36; int tt = (blk / 36) % 32; int b = blk / (36 * 32);
    int c0 = ct * 64, t0 = tt * 64;
    int tid = threadIdx.x;
    __shared__ float tile[67 * 64];
    for (int i = tid; i < 67 * 64; i += 256) {
        int r = i >> 6, c = i & 63;
        int t = t0 - 3 + r;
        tile[i] = (t >= 0) ? xin[((long)(b * T + t)) * CCH + c0 + c] : 0.f;
    }
    __syncthreads();
    int c = tid & 63; int rb = (tid >> 6) * 16;
    int gc = c0 + c;
    double w0 = cw[gc * 4], w1 = cw[gc * 4 + 1], w2 = cw[gc * 4 + 2], w3 = cw[gc * 4 + 3];
    double bias = cb[gc];
    for (int j = 0; j < 16; j++) {
        int tl = rb + j;
        double a = bias + w0 * (double)tile[tl * 64 + c] + w1 * (double)tile[(tl + 1) * 64 + c]
                        + w2 * (double)tile[(tl + 2) * 64 + c] + w3 * (double)tile[(tl + 3) * 64 + c];
        xbc[((long)(b * T + t0 + tl)) * CCH + gc] = (float)(a * sigd(a));
    }
}

// ---------------------------------------------------------- SSM scan v10-A
#define SCAN_STEP(tt) do { \
    int slot_ = (tt) & 7; \
    float dtv_ = sdt[(tt)], dav_ = sda[(tt)]; \
    float xt0_ = sx[slot_][pp], xt1_ = sx[slot_][pp + 8]; \
    float dtx0_ = dtv_ * xt0_, dtx1_ = dtv_ * xt1_; \
    const float4* BP_ = (const float4*)&sbc[slot_][0]; \
    float y0a_ = 0.f, y0b_ = 0.f, y1a_ = 0.f, y1b_ = 0.f; \
    _Pragma("unroll") \
    for (int r_ = 0; r_ < 4; r_++) { \
        float4 bv_ = BP_[r_ * 8 + sub]; \
        float4 cv_ = BP_[32 + r_ * 8 + sub]; \
        hs0[r_*4+0] = fmaf(dav_, hs0[r_*4+0], dtx0_ * bv_.x); y0a_ = fmaf(hs0[r_*4+0], cv_.x, y0a_); \
        hs0[r_*4+1] = fmaf(dav_, hs0[r_*4+1], dtx0_ * bv_.y); y0b_ = fmaf(hs0[r_*4+1], cv_.y, y0b_); \
        hs0[r_*4+2] = fmaf(dav_, hs0[r_*4+2], dtx0_ * bv_.z); y0a_ = fmaf(hs0[r_*4+2], cv_.z, y0a_); \
        hs0[r_*4+3] = fmaf(dav_, hs0[r_*4+3], dtx0_ * bv_.w); y0b_ = fmaf(hs0[r_*4+3], cv_.w, y0b_); \
        hs1[r_*4+0] = fmaf(dav_, hs1[r_*4+0], dtx1_ * bv_.x); y1a_ = fmaf(hs1[r_*4+0], cv_.x, y1a_); \
        hs1[r_*4+1] = fmaf(dav_, hs1[r_*4+1], dtx1_ * bv_.y); y1b_ = fmaf(hs1[r_*4+1], cv_.y, y1b_); \
        hs1[r_*4+2] = fmaf(dav_, hs1[r_*4+2], dtx1_ * bv_.z); y1a_ = fmaf(hs1[r_*4+2], cv_.z, y1a_); \
        hs1[r_*4+3] = fmaf(dav_, hs1[r_*4+3], dtx1_ * bv_.w); y1b_ = fmaf(hs1[r_*4+3], cv_.w, y1b_); \
    } \
    float y0_ = y0a_ + y0b_, y1_ = y1a_ + y1b_; \
    y0_ += __shfl_xor(y0_, 1); y0_ += __shfl_xor(y0_, 2); y0_ += __shfl_xor(y0_, 4); \
    y1_ += __shfl_xor(y1_, 1); y1_ += __shfl_xor(y1_, 2); y1_ += __shfl_xor(y1_, 4); \
    if (sub == 0) { \
        yout[(long)(tt) * DIN] = y0_ + sDp * xt0_; \
        yout[(long)(tt) * DIN + 8] = y1_ + sDp * xt1_; \
    } \
    runA *= dav_; \
    if (wrc && l == 0) cumAp[(tt)] = runA; \
} while (0)

#define SCAN_ISSUE(s) do { \
    GLOAD16(bcsrc + (long)(s) * CCH, &sbc[(s) & 7][0]); \
    GLOAD4(xsrc + (long)(s) * CCH, &sx[(s) & 7][0]); \
} while (0)

__global__ __launch_bounds__(64) void scan_kernel(const float* __restrict__ xbc, const float* __restrict__ dtb,
                                                  const float* __restrict__ dab, const float* __restrict__ Dp,
                                                  float* __restrict__ ys, float* __restrict__ hend,
                                                  float* __restrict__ cumA) {
    int bx = blockIdx.x;
    int b = bx >> 10, h = (bx >> 5) & 31, c = (bx >> 2) & 7, q4 = bx & 3;
    int l = threadIdx.x;
    int sub = l & 7, pp = l >> 3;
    __shared__ __align__(16) float sbc[8][256];   // 8 slots x (B[128] || C[128])
    __shared__ __align__(16) float sx[8][64];     // 8 slots x x-16 (16 used)
    __shared__ float sdt[CL];
    __shared__ float sda[CL];
    long rowc = (long)b * T + (long)c * CL;        // chunk row base
    const float* bcrow = xbc + rowc * CCH + 2048;
    const float* xrow  = xbc + rowc * CCH + h * 64 + q4 * 16;
    float* yout = ys + rowc * DIN + h * 64 + q4 * 16 + pp;

    int perm = ((l >> 3) & 3) | ((l & 7) << 2) | (l & 32);
    const float* bcsrc = bcrow + perm * 4;
    const float* xsrc  = xrow + (l & 15);

    bool wrc = (q4 == 0);
    float* cumAp = cumA + ((long)(b * 32 + h)) * T + (long)c * CL;
    float runA = 1.f;

    // per-chunk dt/dA preload (gather DMAs, drained by first counted wait)
    for (int i = 0; i < CL / 64; i++) {
        GLOAD4(dtb + (rowc + i * 64 + l) * NH + h, &sdt[i * 64]);
        GLOAD4(dab + (rowc + i * 64 + l) * NH + h, &sda[i * 64]);
    }
    // ring prologue: steps 0..5 (3 iterations ahead)
#pragma unroll
    for (int s = 0; s < 6; s++) SCAN_ISSUE(s);

    float hs0[16], hs1[16];
#pragma unroll
    for (int j = 0; j < 16; j++) { hs0[j] = 0.f; hs1[j] = 0.f; }
    float sDp = Dp[h];

    constexpr int NI = CL / 2;    // 128 iterations, 2 steps each
    for (int i = 0; i < NI - 3; i++) {
        int s0 = 2 * i + 6;
        SCAN_ISSUE(s0);
        SCAN_ISSUE(s0 + 1);
        VMWAIT(12);
        SCAN_STEP(2 * i);
        SCAN_STEP(2 * i + 1);
    }
    { int i = NI - 3; VMWAIT(8); SCAN_STEP(2 * i); SCAN_STEP(2 * i + 1); }
    { int i = NI - 2; VMWAIT(4); SCAN_STEP(2 * i); SCAN_STEP(2 * i + 1); }
    { int i = NI - 1; VMWAIT(0); SCAN_STEP(2 * i); SCAN_STEP(2 * i + 1); }

    // chunk-end states (2 p per lane) -> hend (chunks 0..NC-2)
    if (c < NC - 1) {
        float* hp = hend + (((long)(b * 32 + h)) * (NC - 1) + c) * 8192 + (q4 * 16 + pp) * 128 + sub * 16;
#pragma unroll
        for (int j = 0; j < 16; j += 4) *(float4*)(hp + j) = *(float4*)&hs0[j];
        float* hp1 = hp + 8 * 128;
#pragma unroll
        for (int j = 0; j < 16; j += 4) *(float4*)(hp1 + j) = *(float4*)&hs1[j];
    }
}

// ---------------------------------------------------------- SSM scan v10-B
// fixed[c] = P_c * fixed[c-1] + hend[c],  P_c = cumA[(c+1)*CL - 1]
__global__ __launch_bounds__(256) void scanfix_kernel(float* __restrict__ hend, const float* __restrict__ cumA) {
    int bh = blockIdx.x; int tid = threadIdx.x;
    float P[NC - 1];
#pragma unroll
    for (int c = 1; c < NC - 1; c++) P[c] = cumA[(long)bh * T + (long)(c + 1) * CL - 1];
    float* hb = hend + (long)bh * (NC - 1) * 8192;
    for (int e = tid; e < 8192; e += 256) {
        float acc = hb[e];
#pragma unroll
        for (int c = 1; c < NC - 1; c++) {
            acc = fmaf(P[c], acc, hb[(long)c * 8192 + e]);
            hb[(long)c * 8192 + e] = acc;
        }
    }
}

// ---------------------------------------------------------- SSM scan v10-C
// y[t] += cumA_t * (C_t . Hin[chunk(t)])   for chunks 1..NC-1
// grid = 128 bh x (NC-1) cm x (CL/128) tq
__global__ __launch_bounds__(256) void scancorr_kernel(const float* __restrict__ hend, const float* __restrict__ cumA,
                                                       const float* __restrict__ xbc, float* __restrict__ ys) {
    int blk = blockIdx.x;
    constexpr int TQ = CL / 128;
    int tq = blk % TQ;
    int cm = (blk / TQ) % (NC - 1);   // chunk c = cm+1
    int bh = blk / (TQ * (NC - 1));
    int b = bh >> 5, h = bh & 31;
    int tid = threadIdx.x;
    int p = tid >> 2, nq = tid & 3;
    const float* Hin = hend + ((long)bh * (NC - 1) + cm) * 8192 + p * 128 + nq * 32;
    float hreg[32];
#pragma unroll
    for (int j = 0; j < 32; j += 4) *(float4*)&hreg[j] = *(const float4*)(Hin + j);
    __shared__ float sC[8][128];
    long t0 = (long)(cm + 1) * CL + tq * 128;
    const float* cA = cumA + (long)bh * T;
    for (int tg = 0; tg < 16; tg++) {
        __syncthreads();
        {
            int tt = tg * 8 + (tid >> 5);
            int cc = (tid & 31) * 4;
            *(float4*)&sC[tid >> 5][cc] = *(const float4*)(xbc + ((long)b * T + t0 + tt) * CCH + 2176 + cc);
        }
        __syncthreads();
#pragma unroll
        for (int j = 0; j < 8; j++) {
            long t = t0 + tg * 8 + j;
            const float* Cr = &sC[j][nq * 32];
            float d = 0.f;
#pragma unroll
            for (int k = 0; k < 32; k += 4) {
                float4 cv = *(const float4*)(Cr + k);
                d += hreg[k] * cv.x + hreg[k + 1] * cv.y + hreg[k + 2] * cv.z + hreg[k + 3] * cv.w;
            }
            d += __shfl_xor(d, 1);
            d += __shfl_xor(d, 2);
            if (nq == 0) {
                float ca = cA[t];
                ys[((long)b * T + t) * DIN + h * 64 + p] += ca * d;
            }
        }
    }
}

// -------------------------------------------- rmsnorm(y_scan * silu(z)), in-place
__global__ __launch_bounds__(256) void ssmnorm_kernel(float* __restrict__ ys, const float* __restrict__ z,
                                                      const float* __restrict__ w) {
    long row = blockIdx.x; int tid = threadIdx.x;
    float* yr = ys + row * DIN;
    const float* zr = z + row * DIN;
    double v[8]; double ss = 0.0;
#pragma unroll
    for (int j = 0; j < 8; j++) {
        int c = tid * 8 + j;
        double zz = (double)zr[c];
        double val = (double)yr[c] * (zz * sigd(zz));
        v[j] = val; ss += val * val;
    }
    for (int off = 1; off < 64; off <<= 1) ss += __shfl_xor(ss, off);
    __shared__ double tmp[4];
    if ((tid & 63) == 0) tmp[tid >> 6] = ss;
    __syncthreads();
    double tot = tmp[0] + tmp[1] + tmp[2] + tmp[3];
    double scale = 1.0 / sqrt(tot / (double)DIN + 1e-5);
#pragma unroll
    for (int j = 0; j < 8; j++) {
        int c = tid * 8 + j;
        yr[c] = (float)(v[j] * scale * (double)w[c]);
    }
}

// ------------------------------------------------------- score head (2)
__global__ void score2_kernel(const float* __restrict__ sh, const float* __restrict__ w2,
                              float* __restrict__ scores, double* __restrict__ ssum) {
    int row = blockIdx.x * 4 + (threadIdx.x >> 6);
    int lane = threadIdx.x & 63;
    const float* h = sh + (long)row * 256;
    double a = 0.0;
    for (int j = 0; j < 4; j++) a += (double)h[lane * 4 + j] * (double)w2[lane * 4 + j];
    for (int off = 1; off < 64; off <<= 1) a += __shfl_xor(a, off);
    if (lane == 0) {
        double sc = sigd(a);
        scores[row] = (float)sc;
        atomicAdd(&ssum[row >> 11], sc);
    }
}

// ------------------------------------------------ top-64 (stable argsort)
__global__ void top64_kernel(const float* __restrict__ scores, int* __restrict__ tidx, float* __restrict__ tval) {
    int b = blockIdx.x; int tid = threadIdx.x;
    __shared__ float s[T];
    __shared__ float rv[256];
    __shared__ int ri[256];
    for (int i = tid; i < T; i += 256) s[i] = scores[b * T + i];
    for (int k = 0; k < 64; k++) {
        __syncthreads();
        float best = -1e30f; int bi = 1 << 30;
        for (int i = tid; i < T; i += 256) {
            float v = s[i];
            if (v > best || (v == best && i < bi)) { best = v; bi = i; }
        }
        rv[tid] = best; ri[tid] = bi;
        __syncthreads();
        for (int off = 128; off > 0; off >>= 1) {
            if (tid < off) {
                float v2 = rv[tid + off]; int i2 = ri[tid + off];
                if (v2 > rv[tid] || (v2 == rv[tid] && i2 < ri[tid])) { rv[tid] = v2; ri[tid] = i2; }
            }
            __syncthreads();
        }
        if (tid == 0) { tidx[b * 64 + k] = ri[0]; tval[b * 64 + k] = rv[0]; s[ri[0]] = -1e30f; }
    }
}

// ---------------------------------------------------- summaries (64/b)
__global__ __launch_bounds__(256) void summ_kernel(const float* __restrict__ y, const int* __restrict__ tidx,
                                                   const float* __restrict__ wsum, float* __restrict__ summ) {
    int s = blockIdx.x & 63; int b = blockIdx.x >> 6;
    int tid = threadIdx.x;
    __shared__ float yrow[1024];
    int tok = tidx[b * 64 + s];
    long base = ((long)(b * T + tok));
    for (int i = tid; i < 1024; i += 256) yrow[i] = y[base * 1024 + i];
    __syncthreads();
    double acc = 0.0;
    const float* w = wsum + (long)tid * 1024;
    for (int kk = 0; kk < 1024; kk++) acc += (double)yrow[kk] * (double)w[kk];
    summ[((long)(b * 64 + s)) * 256 + tid] = (float)acc;
}

// -------------------------------------------------------- pool update
__global__ void pool_kernel(const float* __restrict__ pin, const float* __restrict__ prin,
                            const int* __restrict__ cin, const float* __restrict__ tval,
                            const float* __restrict__ summ, const double* __restrict__ ssum,
                            float* __restrict__ pout, float* __restrict__ prout,
                            float* __restrict__ cout, float* __restrict__ rmask) {
    int b = blockIdx.x; int tid = threadIdx.x;
    __shared__ float spri[64];
    __shared__ int scount, sact, sslot, srep, srslot;
    for (int i = tid; i < 64 * 256; i += 256) pout[(long)b * 16384 + i] = pin[(long)b * 16384 + i];
    if (tid < 64) spri[tid] = prin[b * 64 + tid];
    if (tid == 0) scount = cin[b];
    __syncthreads();
    for (int s = 0; s < 64; s++) {
        float imp = tval[b * 64 + s];
        bool has = imp > 0.5f;                       // TAU1
        if (tid == 0) {
            sact = 0;
            if (has && scount < 64) { sslot = scount; spri[scount] = imp; scount++; sact = 1; }
        }
        __syncthreads();
        if (sact) pout[((long)(b * 64 + sslot)) * 256 + tid] = summ[((long)(b * 64 + s)) * 256 + tid];
        if (tid < 64) {
            float v = spri[tid]; int idx = tid;
            for (int off = 1; off < 64; off <<= 1) {
                float v2 = __shfl_xor(v, off); int i2 = __shfl_xor(idx, off);
                if (v2 < v || (v2 == v && i2 < idx)) { v = v2; idx = i2; }
            }
            if (tid == 0) {
                srep = 0;
                if (has && scount >= 64 && imp > v) { srep = 1; srslot = idx; spri[idx] = imp; }
            }
        }
        __syncthreads();
        if (srep) pout[((long)(b * 64 + srslot)) * 256 + tid] = summ[((long)(b * 64 + s)) * 256 + tid];
        __syncthreads();
    }
    if (tid < 64) prout[b * 64 + tid] = spri[tid];
    if (tid == 0) {
        cout[b] = (float)scount;
        double mean = ssum[b] / (double)T;
        rmask[b] = (mean > 0.4 && scount > 0) ? 1.f : 0.f;
    }
}

// ------------------------------------------------------------ k,v proj
__global__ __launch_bounds__(256) void kv_kernel(const float* __restrict__ pool, const float* __restrict__ kw,
                                                 const float* __restrict__ vw, float* __restrict__ k,
                                                 float* __restrict__ v) {
    int blk = blockIdx.x; int b = blk >> 6, s = blk & 63; int tid = threadIdx.x;
    __shared__ float pr[256];
    pr[tid] = pool[((long)(b * 64 + s)) * 256 + tid];
    __syncthreads();
    float a = 0.f;
    const float* w = kw + (long)tid * 256;
    for (int j = 0; j < 256; j++) a = fmaf(pr[j], w[j], a);
    k[((long)(b * 64 + s)) * 256 + tid] = a;
    for (int m = 0; m < 4; m++) {
        int o = m * 256 + tid;
        const float* w2 = vw + (long)o * 256;
        float c = 0.f;
        for (int j = 0; j < 256; j++) c = fmaf(pr[j], w2[j], c);
        v[((long)(b * 64 + s)) * 1024 + o] = c;
    }
}

// ----------------------------------------------------- pool attention
__global__ __launch_bounds__(256) void attn_kernel(const float* __restrict__ q, const float* __restrict__ k,
                                                   const float* __restrict__ v, const float* __restrict__ cout,
                                                   float* __restrict__ concat) {
    long row = blockIdx.x;
    int b = (int)(row >> 11);
    int tid = threadIdx.x;
    int cnt = (int)cout[b];
    __shared__ float qs[256], slog[64], sp[64];
    qs[tid] = q[row * 256 + tid];
    __syncthreads();
    int s = tid >> 2, part = tid & 3;
    const float* kr = k + ((long)(b * 64 + s)) * 256 + part * 64;
    float d = 0.f;
    for (int j = 0; j < 64; j++) d = fmaf(qs[part * 64 + j], kr[j], d);
    d += __shfl_xor(d, 1); d += __shfl_xor(d, 2);
    if (part == 0) slog[s] = d * 0.0625f;
    __syncthreads();
    if (tid < 64) {
        float l = (tid < cnt) ? slog[tid] : -1e30f;
        float m = l;
        for (int off = 1; off < 64; off <<= 1) m = fmaxf(m, __shfl_xor(m, off));
        float e = (tid < cnt) ? expf(l - m) : 0.f;
        float su = e;
        for (int off = 1; off < 64; off <<= 1) su += __shfl_xor(su, off);
        sp[tid] = (cnt > 0) ? e / su : 0.f;
    }
    __syncthreads();
    float acc[4] = {0.f, 0.f, 0.f, 0.f};
    for (int s2 = 0; s2 < cnt; s2++) {
        float p = sp[s2];
        const float* vr = v + ((long)(b * 64 + s2)) * 1024 + tid;
        acc[0] = fmaf(p, vr[0], acc[0]);
        acc[1] = fmaf(p, vr[256], acc[1]);
        acc[2] = fmaf(p, vr[512], acc[2]);
        acc[3] = fmaf(p, vr[768], acc[3]);
    }
    for (int j = 0; j < 4; j++) concat[row * 2048 + 1024 + tid + j * 256] = acc[j];
}

// ===========================================================================
extern "C" void kernel_launch(void* const* d_in, const int* in_sizes, int n_in,
                              void* d_out, int out_size, void* d_ws, size_t ws_size,
                              hipStream_t stream) {
    (void)in_sizes; (void)n_in; (void)out_size;
    const float* x       = (const float*)d_in[0];
    const float* pool_in = (const float*)d_in[1];
    const float* pri_in  = (const float*)d_in[2];
    const int*   cnt_in  = (const int*)d_in[3];
    const float* norm_w  = (const float*)d_in[4];
    const float* in_w    = (const float*)d_in[5];
    const float* conv_w  = (const float*)d_in[6];
    const float* conv_b  = (const float*)d_in[7];
    const float* dt_bias = (const float*)d_in[8];
    const float* A_log   = (const float*)d_in[9];
    const float* Dp      = (const float*)d_in[10];
    const float* ssm_w   = (const float*)d_in[11];
    const float* out_w   = (const float*)d_in[12];
    const float* s_w1    = (const float*)d_in[13];
    const float* s_w2    = (const float*)d_in[14];
    const float* summ_w  = (const float*)d_in[15];
    const float* q_w     = (const float*)d_in[16];
    const float* k_w     = (const float*)d_in[17];
    const float* v_w     = (const float*)d_in[18];
    const float* gate_w  = (const float*)d_in[19];

    float* outy    = (float*)d_out;
    float* outpool = outy + (long)ROWS * D;
    float* outpri  = outpool + Bb * 64 * 256;
    float* outcnt  = outpri + Bb * 64;

    char* ws = (char*)d_ws;
    size_t cur = 0;
    auto alloc = [&](size_t bytes) { size_t o = cur; cur += (bytes + 255) / 256 * 256; return o; };

    size_t pw_in_bytes   = (size_t)2 * DPROJ * 1024 * 2;   // 17.9 MB
    size_t ra_bytes = (size_t)ROWS * CCH * 4;              // 75.5 MB >= planes 51.5

    size_t o_dt   = alloc((size_t)ROWS * NH * 4);
    size_t o_da   = alloc((size_t)ROWS * NH * 4);
    size_t o_sc   = alloc((size_t)ROWS * 4);
    size_t o_ssum = alloc(64);
    size_t o_rmk  = alloc(64);
    size_t o_tidx = alloc(Bb * 64 * 4);
    size_t o_tval = alloc(Bb * 64 * 4);
    size_t o_summ = alloc((size_t)Bb * 64 * 256 * 4);
    size_t o_k    = alloc((size_t)Bb * 64 * 256 * 4);
    size_t o_v    = alloc((size_t)Bb * 64 * 1024 * 4);
    size_t o_cumA = alloc((size_t)128 * T * 4);                // 1 MB
    size_t o_RA = alloc(ra_bytes);                 // pw_in+uplanes -> xbc -> concat+sch
    size_t o_RB = alloc((size_t)ROWS * DIN * 4);   // bufZ -> out_w/s_w1 planes -> qbuf
    size_t o_RC = alloc((size_t)ROWS * CCH * 4);   // bufX -> yscan/normed (in-place)

    if (ws_size < cur) {   // diagnostic: report ws_size in MB via absmax
        diag_kernel<<<1, 64, 0, stream>>>(outy, 1000.0f + (float)(ws_size >> 20));
        return;
    }

    float* dtb    = (float*)(ws + o_dt);
    float* dab    = (float*)(ws + o_da);
    float* scores = (float*)(ws + o_sc);
    double* ssum  = (double*)(ws + o_ssum);
    float* rmk    = (float*)(ws + o_rmk);
    int*   tidx   = (int*)(ws + o_tidx);
    float* tval   = (float*)(ws + o_tval);
    float* summ   = (float*)(ws + o_summ);
    float* kbuf   = (float*)(ws + o_k);
    float* vbuf   = (float*)(ws + o_v);
    float* cumA   = (float*)(ws + o_cumA);
    // hend (29.4 MB = 128*(NC-1)*8192 floats) lives in the DEAD outy region
    // of d_out: first written at scan (step 4), last read at scancorr (4c),
    // fully overwritten by out_proj (step 6).  outy = 33.5 MB >= 29.4 MB.
    float* hend   = outy;

    u16*  pw_in   = (u16*)(ws + o_RA);
    u16*  uplanes = (u16*)(ws + o_RA + pw_in_bytes);
    float* xbc    = (float*)(ws + o_RA);
    float* concat = (float*)(ws + o_RA);
    float* sch    = (float*)(ws + o_RA + (size_t)ROWS * DIN * 4);
    float* bufZ   = (float*)(ws + o_RB);
    u16*  pw_out  = (u16*)(ws + o_RB);
    u16*  pw_s1   = (u16*)(ws + o_RB + (size_t)16 * 1024 * 1024);
    float* qbuf   = (float*)(ws + o_RB);
    float* bufX   = (float*)(ws + o_RC);
    float* yscan  = (float*)(ws + o_RC);

    // 0. init + in_w plane split (RA is dead until conv)
    zerod_kernel<<<1, 64, 0, stream>>>(ssum, 4);
    {
        long n = (long)DPROJ * 1024;
        split2_kernel<<<(n + 255) / 256, 256, 0, stream>>>(in_w, pw_in, n);
    }
    // 1. rmsnorm(x) -> u as 2 fp16 planes (RA, behind pw_in)
    rms_x_kernel<<<ROWS, 256, 0, stream>>>(x, norm_w, uplanes, (long)ROWS * D);
    // 2. in_proj (fp16 2-plane, A+B pre-split DMA): -> bufZ, bufX, dt/dA
    gemm_f32<2, 0, true, true><<<dim3(35, 64), 256, 0, stream>>>(
        nullptr, 0, uplanes, (size_t)ROWS * D,
        nullptr, 0, pw_in, (size_t)DPROJ * 1024,
        ROWS, DPROJ, 1024,
        bufZ, bufX, dt_bias, A_log, dtb, dab);
    // 3. conv + silu (f64 math) -> xbc (R_A, over dead planes)
    conv_kernel<<<Bb * 32 * 36, 256, 0, stream>>>(bufX, conv_w, conv_b, xbc);
    // 4. scan v10: NC=8 chunked phase A + boundary prefix + correction
    scan_kernel<<<Bb * NH * NC * 4, 64, 0, stream>>>(xbc, dtb, dab, Dp, yscan, hend, cumA);
    scanfix_kernel<<<128, 256, 0, stream>>>(hend, cumA);
    scancorr_kernel<<<128 * (NC - 1) * (CL / 128), 256, 0, stream>>>(hend, cumA, xbc, yscan);
    // 5. ssm rmsnorm (f64, in-place over yscan); bufZ dead after this
    ssmnorm_kernel<<<ROWS, 256, 0, stream>>>(yscan, bufZ, ssm_w);
    // 5b. out_w + s_w1 plane splits into dead R_B
    {
        long n = (long)1024 * 2048;
        split2_kernel<<<(n + 255) / 256, 256, 0, stream>>>(out_w, pw_out, n);
        long n2 = (long)256 * 1024;
        split2_kernel<<<(n2 + 255) / 256, 256, 0, stream>>>(s_w1, pw_s1, n2);
    }
    // 6. out_proj (fp16 2-plane, DMA B) + residual -> outy, concat (R_A)
    gemm_f32<2, 2, true, false><<<dim3(8, 64), 256, 0, stream>>>(
        yscan, 2048, nullptr, 0,
        nullptr, 0, pw_out, (size_t)1024 * 2048,
        ROWS, 1024, 2048,
        outy, concat, x, nullptr, nullptr, nullptr);
    // 7. score1 (fp16 2-plane, DMA B, relu) -> sch
    gemm_f32<2, 1, true, false><<<dim3(2, 64), 256, 0, stream>>>(
        outy, 1024, nullptr, 0,
        nullptr, 0, pw_s1, (size_t)256 * 1024,
        ROWS, 256, 1024,
        sch, nullptr, nullptr, nullptr, nullptr, nullptr);
    // 8. score2 (f64) -> scores, ssum
    score2_kernel<<<ROWS / 4, 256, 0, stream>>>(sch, s_w2, scores, ssum);
    // 9. top-64
    top64_kernel<<<Bb, 256, 0, stream>>>(scores, tidx, tval);
    // 10. summaries (f32 y, f64 accum)
    summ_kernel<<<Bb * 64, 256, 0, stream>>>(outy, tidx, summ_w, summ);
    // 11. pool update -> d_out pool/pri/counts + rmask
    pool_kernel<<<Bb, 256, 0, stream>>>(pool_in, pri_in, cnt_in, tval, summ, ssum,
                                        outpool, outpri, outcnt, rmk);
    // 12. k, v
    kv_kernel<<<Bb * 64, 256, 0, stream>>>(outpool, k_w, v_w, kbuf, vbuf);
    // 13. q = y @ q_w^T (fp16 single-plane); qbuf overlays dead out_w planes
    gemm_f32<1, 3, false, false><<<dim3(2, 64), 256, 0, stream>>>(
        outy, 1024, nullptr, 0,
        q_w, 1024, nullptr, 0,
        ROWS, 256, 1024,
        qbuf, nullptr, nullptr, nullptr, nullptr, nullptr);
    // 14. attention -> retrieved (f32, concat second half)
    attn_kernel<<<ROWS, 256, 0, stream>>>(qbuf, kbuf, vbuf, outcnt, concat);
    // 15. gate GEMM (fp16 single-plane) + final y update
    gemm_f32<1, 4, false, false><<<dim3(8, 64), 256, 0, stream>>>(
        concat, 2048, nullptr, 0,
        gate_w, 2048, nullptr, 0,
        ROWS, 1024, 2048,
        outy, nullptr, concat, rmk, nullptr, nullptr);
}

// Round 19
// 1696.652 us; speedup vs baseline: 1.0109x; 1.0109x over previous
//
#include <hip/hip_runtime.h>

// ---------------------------------------------------------------------------
// MemMambaBlock on MI355X.  B=4 T=2048 D=1024 D_INNER=2048 D_STATE=128
// NHEADS=32 HEADDIM=64 D_CONV=4 POOL=64 SUMDIM=256 d_in_proj=4384
// R19: conv_kernel + ssmnorm_kernel elementwise math f64 -> f32 (the
// reference computes silu/rmsnorm in f32; our f64 was 18.9M + 16.8M f64
// exp() calls of hidden VALU time, ~300-400us).  Error ~1e-7 rel -- an
// order below the passing ~1e-6 chunk-recomposition class.
// Scan v10 (kept): NC=8 chunked linear scan, hend in dead d_out region.
// GEMM v9 (kept): fp16 2-plane split + per-pass fragments + chunk swizzle +
// 2-phase double-buffered K-loop, (256,2).  f64 score head + dt/dA epilogue.
// ---------------------------------------------------------------------------

using u16 = unsigned short;
using f16x8 = __attribute__((ext_vector_type(8))) _Float16;
using f32x4  = __attribute__((ext_vector_type(4))) float;

#define DEV __device__ __forceinline__

#define GLOAD4(g, l)  __builtin_amdgcn_global_load_lds((const __attribute__((address_space(1))) void*)(g), (__attribute__((address_space(3))) void*)(l), 4, 0, 0)
#define GLOAD16(g, l) __builtin_amdgcn_global_load_lds((const __attribute__((address_space(1))) void*)(g), (__attribute__((address_space(3))) void*)(l), 16, 0, 0)
#define VMWAIT(N) asm volatile("s_waitcnt vmcnt(" #N ")" ::: "memory")

static constexpr int Bb = 4, T = 2048, D = 1024;
static constexpr int DIN = 2048, DST = 128, NH = 32;
static constexpr int DPROJ = 4384;          // 2*DIN + 2*DST + NH
static constexpr int CCH = 2304;            // DIN + 2*DST (conv channels)
static constexpr int ROWS = Bb * T;         // 8192
static constexpr int NC = 8, CL = 256;      // chunks x chunk length
static constexpr float RSC = 4096.f, RSCI = 1.f / 4096.f;

DEV u16 f2h_bits(float f) { union { _Float16 h; u16 u; } v; v.h = (_Float16)f; return v.u; }
DEV float h2f(u16 u) { union { _Float16 h; u16 u; } v; v.u = u; return (float)v.h; }
DEV double sigd(double x) { return 1.0 / (1.0 + exp(-x)); }
DEV float sigf(float x) { return 1.f / (1.f + expf(-x)); }
DEV int swz(int c) { return c ^ ((c >> 3) & 3); }   // involution, row-preserving

__global__ void diag_kernel(float* o, float v) { if (threadIdx.x == 0) o[0] = v; }
__global__ void zerod_kernel(double* p, int n) { if ((int)threadIdx.x < n) p[threadIdx.x] = 0.0; }

// ------------------------------------- 2-plane fp16 split (scaled residual)
__global__ void split2_kernel(const float* __restrict__ in, u16* __restrict__ out, long n) {
    long i = (long)blockIdx.x * 256 + threadIdx.x;
    if (i >= n) return;
    float v = in[i];
    u16 h = f2h_bits(v);
    float r1 = (v - h2f(h)) * RSC;
    out[i] = h;
    out[n + i] = f2h_bits(r1);
}

// ------------------------------------------- rmsnorm(x) -> 2 fp16 planes
__global__ __launch_bounds__(256) void rms_x_kernel(const float* __restrict__ x, const float* __restrict__ w,
                                                    u16* __restrict__ up, long pstride) {
    long row = blockIdx.x; int tid = threadIdx.x;
    const float* xr = x + row * D;
    float4 xv = *(const float4*)(xr + tid * 4);
    double ss = (double)xv.x * xv.x + (double)xv.y * xv.y + (double)xv.z * xv.z + (double)xv.w * xv.w;
    for (int off = 1; off < 64; off <<= 1) ss += __shfl_xor(ss, off);
    __shared__ double tmp[4];
    if ((tid & 63) == 0) tmp[tid >> 6] = ss;
    __syncthreads();
    double tot = tmp[0] + tmp[1] + tmp[2] + tmp[3];
    double scale = 1.0 / sqrt(tot / (double)D + 1e-4);
    float4 wv = *(const float4*)(w + tid * 4);
    long base = row * D + tid * 4;
    float vals[4];
    vals[0] = (float)((double)xv.x * scale * (double)wv.x);
    vals[1] = (float)((double)xv.y * scale * (double)wv.y);
    vals[2] = (float)((double)xv.z * scale * (double)wv.z);
    vals[3] = (float)((double)xv.w * scale * (double)wv.w);
#pragma unroll
    for (int j = 0; j < 4; j++) {
        float f = vals[j];
        u16 h = f2h_bits(f);
        up[base + j] = h;
        up[pstride + base + j] = f2h_bits((f - h2f(h)) * RSC);
    }
}

// ----------------------------------------------------------------- GEMM
// Row-major tiles [128][32] u16 viewed as 512 16B chunks (c = row*4 + q);
// physical placement swizzled by s(c) = c ^ ((c>>3)&3).
template <int NP>
DEV void stage_one(u16* s0, u16* s1, const float* __restrict__ src, long ld,
                   int row0, int lastrow, int k0, int tid) {
    int r = tid >> 1, cb = (tid & 1) * 2;       // chunk-col base (0 or 2)
    long rg = row0 + r; if (rg > lastrow) rg = lastrow;
    const float* p = src + rg * ld + k0 + cb * 8;
    u16 h16[16], l16[16];
#pragma unroll
    for (int q = 0; q < 4; q++) {
        float4 v4 = *(const float4*)(p + q * 4);
        float vv[4] = { v4.x, v4.y, v4.z, v4.w };
#pragma unroll
        for (int j = 0; j < 4; j++) {
            float xv = vv[j];
            u16 h = f2h_bits(xv);
            h16[q * 4 + j] = h;
            if constexpr (NP == 2) l16[q * 4 + j] = f2h_bits((xv - h2f(h)) * RSC);
        }
    }
    int o0 = swz(r * 4 + cb) * 8, o1 = swz(r * 4 + cb + 1) * 8;
    *(uint4*)(s0 + o0) = *(const uint4*)(h16);
    *(uint4*)(s0 + o1) = *(const uint4*)(h16 + 8);
    if constexpr (NP == 2) {
        *(uint4*)(s1 + o0) = *(const uint4*)(l16);
        *(uint4*)(s1 + o1) = *(const uint4*)(l16 + 8);
    }
}

// DMA staging: LDS chunk s (linear dest) holds global chunk swz(s); wave
// quarter still covers the same contiguous 1KB global span (coalesced).
DEV void stage_pre_dma(u16* dst, const u16* __restrict__ src, long ld,
                       int row0, int lastrow, int k0, int wid, int lane) {
#pragma unroll
    for (int j = 0; j < 2; j++) {
        int s = wid * 128 + j * 64 + lane;
        int g = swz(s);
        int r = g >> 2, cs = g & 3;
        long rg = row0 + r; if (rg > lastrow) rg = lastrow;
        const u16* gp = src + rg * ld + k0 + cs * 8;
        GLOAD16(gp, dst + (wid * 128 + j * 64) * 8);
    }
}

// stage one K-tile (all planes, A+B) into buffer base bb
#define STAGE_TILE(bb, k0_) do { \
    u16* As0_ = (bb); \
    u16* As1_ = (bb) + 4096; \
    u16* Bs0_ = (bb) + NP * 4096; \
    u16* Bs1_ = (bb) + NP * 4096 + 4096; \
    if constexpr (BP) { \
        stage_pre_dma(Bs0_, Bp, K, tN, N - 1, (k0_), wid, lane); \
        if constexpr (NP == 2) stage_pre_dma(Bs1_, Bp + bstride, K, tN, N - 1, (k0_), wid, lane); \
    } \
    if constexpr (AP) { \
        stage_pre_dma(As0_, Ap, K, tM, M - 1, (k0_), wid, lane); \
        if constexpr (NP == 2) stage_pre_dma(As1_, Ap + astride, K, tM, M - 1, (k0_), wid, lane); \
    } else { \
        stage_one<NP>(As0_, NP == 2 ? As1_ : nullptr, A, lda, tM, M - 1, (k0_), tid); \
    } \
    if constexpr (!BP) { \
        stage_one<NP>(Bs0_, NP == 2 ? Bs1_ : nullptr, B, ldb, tN, N - 1, (k0_), tid); \
    } \
} while (0)

template <int NP, int MODE, bool BP, bool AP>
__global__ __launch_bounds__(256, 2) void gemm_f32(
    const float* __restrict__ A, long lda,
    const u16* __restrict__ Ap, size_t astride,
    const float* __restrict__ B, long ldb,
    const u16* __restrict__ Bp, size_t bstride,
    int M, int N, int K,
    float* __restrict__ out0, float* __restrict__ out1,
    const float* __restrict__ aux0, const float* __restrict__ aux1,
    float* __restrict__ dtb, float* __restrict__ dab) {
    __shared__ __align__(16) u16 sm[2 * NP * 2 * 4096];   // double-buffered
    int tid = threadIdx.x, lane = tid & 63, wid = tid >> 6;
    int wr = wid >> 1, wc = wid & 1;
    int nwg = gridDim.x * gridDim.y;
    int wg = blockIdx.y * gridDim.x + blockIdx.x;
    int lin = (wg & 7) * (nwg >> 3) + (wg >> 3);
    int tM = (lin / gridDim.x) * 128, tN = (lin % gridDim.x) * 128;

    f32x4 acc1[4][4], acc2[4][4];
#pragma unroll
    for (int i = 0; i < 4; i++)
#pragma unroll
        for (int j = 0; j < 4; j++) {
            acc1[i][j] = f32x4{0.f, 0.f, 0.f, 0.f};
            if constexpr (NP == 2) acc2[i][j] = f32x4{0.f, 0.f, 0.f, 0.f};
        }

    int rA = wr * 64 + (lane & 15);
    int rB = wc * 64 + (lane & 15);
    int kc = lane >> 4;
    // precomputed swizzled fragment offsets (u16 units)
    int oA[4], oB[4];
#pragma unroll
    for (int i = 0; i < 4; i++) {
        oA[i] = swz((rA + i * 16) * 4 + kc) * 8;
        oB[i] = swz((rB + i * 16) * 4 + kc) * 8;
    }

    int nsteps = K / 32;
    int cur = 0;
    STAGE_TILE(sm, 0);
    __syncthreads();                         // drains prologue DMA + ds_writes
    for (int kt = 0; kt < nsteps; ++kt) {
        u16* cb = sm + cur * (NP * 2 * 4096);
        if (kt + 1 < nsteps) {
            u16* nb = sm + (cur ^ 1) * (NP * 2 * 4096);
            STAGE_TILE(nb, (kt + 1) * 32);   // DMA overlaps this tile's MFMA
        }
        u16* As0 = cb; u16* As1 = cb + 4096;
        u16* Bs0 = cb + NP * 4096; u16* Bs1 = cb + NP * 4096 + 4096;
        f16x8 fa[4], fb[4];
        // pass 1: A0 x B0 -> acc1
#pragma unroll
        for (int i = 0; i < 4; i++) {
            fa[i] = *(const f16x8*)(As0 + oA[i]);
            fb[i] = *(const f16x8*)(Bs0 + oB[i]);
        }
#pragma unroll
        for (int mi = 0; mi < 4; mi++)
#pragma unroll
            for (int ni = 0; ni < 4; ni++)
                acc1[mi][ni] = __builtin_amdgcn_mfma_f32_16x16x32_f16(fa[mi], fb[ni], acc1[mi][ni], 0, 0, 0);
        if constexpr (NP == 2) {
            // pass 2: A0 x B1 -> acc2   (fa still holds A0)
#pragma unroll
            for (int i = 0; i < 4; i++) fb[i] = *(const f16x8*)(Bs1 + oB[i]);
#pragma unroll
            for (int mi = 0; mi < 4; mi++)
#pragma unroll
                for (int ni = 0; ni < 4; ni++)
                    acc2[mi][ni] = __builtin_amdgcn_mfma_f32_16x16x32_f16(fa[mi], fb[ni], acc2[mi][ni], 0, 0, 0);
            // pass 3: A1 x B0 -> acc2
#pragma unroll
            for (int i = 0; i < 4; i++) {
                fa[i] = *(const f16x8*)(As1 + oA[i]);
                fb[i] = *(const f16x8*)(Bs0 + oB[i]);
            }
#pragma unroll
            for (int mi = 0; mi < 4; mi++)
#pragma unroll
                for (int ni = 0; ni < 4; ni++)
                    acc2[mi][ni] = __builtin_amdgcn_mfma_f32_16x16x32_f16(fa[mi], fb[ni], acc2[mi][ni], 0, 0, 0);
        }
        if (kt + 1 < nsteps) {
            __syncthreads();                 // drains next-tile DMA (hidden under MFMA)
            cur ^= 1;
        }
    }
    int laneh = lane >> 4, lanel = lane & 15;
#pragma unroll
    for (int mi = 0; mi < 4; mi++)
#pragma unroll
        for (int ni = 0; ni < 4; ni++) {
            int col = tN + wc * 64 + ni * 16 + lanel;
            if (col >= N) continue;
#pragma unroll
            for (int r = 0; r < 4; r++) {
                long row = tM + wr * 64 + mi * 16 + laneh * 4 + r;
                float v = acc1[mi][ni][r];
                if constexpr (NP == 2) v += acc2[mi][ni][r] * RSCI;
                if constexpr (MODE == 0) {
                    if (col < 2048) out0[row * 2048 + col] = v;
                    else if (col < 4352) out1[row * 2304 + (col - 2048)] = v;
                    else {
                        int h = col - 4352;
                        double xx = (double)v + (double)aux0[h];
                        double sp = (xx > 30.0) ? xx : log1p(exp(xx));
                        double a = -exp((double)aux1[h]);
                        dtb[row * NH + h] = (float)sp;
                        dab[row * NH + h] = (float)exp(sp * a);
                    }
                } else if constexpr (MODE == 1) {
                    out0[row * 256 + col] = fmaxf(v, 0.f);
                } else if constexpr (MODE == 2) {
                    float y = aux0[row * 1024 + col] + v;
                    out0[row * 1024 + col] = y;
                    out1[row * 2048 + col] = y;
                } else if constexpr (MODE == 3) {
                    out0[row * 256 + col] = v;
                } else {
                    double g = sigd((double)v);
                    float retr = aux0[row * 2048 + 1024 + col];
                    out0[row * 1024 + col] += (float)(g * (double)retr * (double)aux1[row >> 11]);
                }
            }
        }
}

// ------------------------------------------------- depthwise causal conv4
__global__ __launch_bounds__(256) void conv_kernel(const float* __restrict__ xin, const float* __restrict__ cw,
                                                   const float* __restrict__ cb, float* __restrict__ xbc) {
    int blk = blockIdx.x;
    int ct = blk % 36; int tt = (blk / 36) % 32; int b = blk / (36 * 32);
    int c0 = ct * 64, t0 = tt * 64;
    int tid = threadIdx.x;
    __shared__ float tile[67 * 64];
    for (int i = tid; i < 67 * 64; i += 256) {
        int r = i >> 6, c = i & 63;
        int t = t0 - 3 + r;
        tile[i] = (t >= 0) ? xin[((long)(b * T + t)) * CCH + c0 + c] : 0.f;
    }
    __syncthreads();
    int c = tid & 63; int rb = (tid >> 6) * 16;
    int gc = c0 + c;
    float w0 = cw[gc * 4], w1 = cw[gc * 4 + 1], w2 = cw[gc * 4 + 2], w3 = cw[gc * 4 + 3];
    float bias = cb[gc];
    for (int j = 0; j < 16; j++) {
        int tl = rb + j;
        float a = bias + w0 * tile[tl * 64 + c] + w1 * tile[(tl + 1) * 64 + c]
                       + w2 * tile[(tl + 2) * 64 + c] + w3 * tile[(tl + 3) * 64 + c];
        xbc[((long)(b * T + t0 + tl)) * CCH + gc] = a * sigf(a);
    }
}

// ---------------------------------------------------------- SSM scan v10-A
#define SCAN_STEP(tt) do { \
    int slot_ = (tt) & 7; \
    float dtv_ = sdt[(tt)], dav_ = sda[(tt)]; \
    float xt0_ = sx[slot_][pp], xt1_ = sx[slot_][pp + 8]; \
    float dtx0_ = dtv_ * xt0_, dtx1_ = dtv_ * xt1_; \
    const float4* BP_ = (const float4*)&sbc[slot_][0]; \
    float y0a_ = 0.f, y0b_ = 0.f, y1a_ = 0.f, y1b_ = 0.f; \
    _Pragma("unroll") \
    for (int r_ = 0; r_ < 4; r_++) { \
        float4 bv_ = BP_[r_ * 8 + sub]; \
        float4 cv_ = BP_[32 + r_ * 8 + sub]; \
        hs0[r_*4+0] = fmaf(dav_, hs0[r_*4+0], dtx0_ * bv_.x); y0a_ = fmaf(hs0[r_*4+0], cv_.x, y0a_); \
        hs0[r_*4+1] = fmaf(dav_, hs0[r_*4+1], dtx0_ * bv_.y); y0b_ = fmaf(hs0[r_*4+1], cv_.y, y0b_); \
        hs0[r_*4+2] = fmaf(dav_, hs0[r_*4+2], dtx0_ * bv_.z); y0a_ = fmaf(hs0[r_*4+2], cv_.z, y0a_); \
        hs0[r_*4+3] = fmaf(dav_, hs0[r_*4+3], dtx0_ * bv_.w); y0b_ = fmaf(hs0[r_*4+3], cv_.w, y0b_); \
        hs1[r_*4+0] = fmaf(dav_, hs1[r_*4+0], dtx1_ * bv_.x); y1a_ = fmaf(hs1[r_*4+0], cv_.x, y1a_); \
        hs1[r_*4+1] = fmaf(dav_, hs1[r_*4+1], dtx1_ * bv_.y); y1b_ = fmaf(hs1[r_*4+1], cv_.y, y1b_); \
        hs1[r_*4+2] = fmaf(dav_, hs1[r_*4+2], dtx1_ * bv_.z); y1a_ = fmaf(hs1[r_*4+2], cv_.z, y1a_); \
        hs1[r_*4+3] = fmaf(dav_, hs1[r_*4+3], dtx1_ * bv_.w); y1b_ = fmaf(hs1[r_*4+3], cv_.w, y1b_); \
    } \
    float y0_ = y0a_ + y0b_, y1_ = y1a_ + y1b_; \
    y0_ += __shfl_xor(y0_, 1); y0_ += __shfl_xor(y0_, 2); y0_ += __shfl_xor(y0_, 4); \
    y1_ += __shfl_xor(y1_, 1); y1_ += __shfl_xor(y1_, 2); y1_ += __shfl_xor(y1_, 4); \
    if (sub == 0) { \
        yout[(long)(tt) * DIN] = y0_ + sDp * xt0_; \
        yout[(long)(tt) * DIN + 8] = y1_ + sDp * xt1_; \
    } \
    runA *= dav_; \
    if (wrc && l == 0) cumAp[(tt)] = runA; \
} while (0)

#define SCAN_ISSUE(s) do { \
    GLOAD16(bcsrc + (long)(s) * CCH, &sbc[(s) & 7][0]); \
    GLOAD4(xsrc + (long)(s) * CCH, &sx[(s) & 7][0]); \
} while (0)

__global__ __launch_bounds__(64) void scan_kernel(const float* __restrict__ xbc, const float* __restrict__ dtb,
                                                  const float* __restrict__ dab, const float* __restrict__ Dp,
                                                  float* __restrict__ ys, float* __restrict__ hend,
                                                  float* __restrict__ cumA) {
    int bx = blockIdx.x;
    int b = bx >> 10, h = (bx >> 5) & 31, c = (bx >> 2) & 7, q4 = bx & 3;
    int l = threadIdx.x;
    int sub = l & 7, pp = l >> 3;
    __shared__ __align__(16) float sbc[8][256];   // 8 slots x (B[128] || C[128])
    __shared__ __align__(16) float sx[8][64];     // 8 slots x x-16 (16 used)
    __shared__ float sdt[CL];
    __shared__ float sda[CL];
    long rowc = (long)b * T + (long)c * CL;        // chunk row base
    const float* bcrow = xbc + rowc * CCH + 2048;
    const float* xrow  = xbc + rowc * CCH + h * 64 + q4 * 16;
    float* yout = ys + rowc * DIN + h * 64 + q4 * 16 + pp;

    int perm = ((l >> 3) & 3) | ((l & 7) << 2) | (l & 32);
    const float* bcsrc = bcrow + perm * 4;
    const float* xsrc  = xrow + (l & 15);

    bool wrc = (q4 == 0);
    float* cumAp = cumA + ((long)(b * 32 + h)) * T + (long)c * CL;
    float runA = 1.f;

    // per-chunk dt/dA preload (gather DMAs, drained by first counted wait)
    for (int i = 0; i < CL / 64; i++) {
        GLOAD4(dtb + (rowc + i * 64 + l) * NH + h, &sdt[i * 64]);
        GLOAD4(dab + (rowc + i * 64 + l) * NH + h, &sda[i * 64]);
    }
    // ring prologue: steps 0..5 (3 iterations ahead)
#pragma unroll
    for (int s = 0; s < 6; s++) SCAN_ISSUE(s);

    float hs0[16], hs1[16];
#pragma unroll
    for (int j = 0; j < 16; j++) { hs0[j] = 0.f; hs1[j] = 0.f; }
    float sDp = Dp[h];

    constexpr int NI = CL / 2;    // 128 iterations, 2 steps each
    for (int i = 0; i < NI - 3; i++) {
        int s0 = 2 * i + 6;
        SCAN_ISSUE(s0);
        SCAN_ISSUE(s0 + 1);
        VMWAIT(12);
        SCAN_STEP(2 * i);
        SCAN_STEP(2 * i + 1);
    }
    { int i = NI - 3; VMWAIT(8); SCAN_STEP(2 * i); SCAN_STEP(2 * i + 1); }
    { int i = NI - 2; VMWAIT(4); SCAN_STEP(2 * i); SCAN_STEP(2 * i + 1); }
    { int i = NI - 1; VMWAIT(0); SCAN_STEP(2 * i); SCAN_STEP(2 * i + 1); }

    // chunk-end states (2 p per lane) -> hend (chunks 0..NC-2)
    if (c < NC - 1) {
        float* hp = hend + (((long)(b * 32 + h)) * (NC - 1) + c) * 8192 + (q4 * 16 + pp) * 128 + sub * 16;
#pragma unroll
        for (int j = 0; j < 16; j += 4) *(float4*)(hp + j) = *(float4*)&hs0[j];
        float* hp1 = hp + 8 * 128;
#pragma unroll
        for (int j = 0; j < 16; j += 4) *(float4*)(hp1 + j) = *(float4*)&hs1[j];
    }
}

// ---------------------------------------------------------- SSM scan v10-B
// fixed[c] = P_c * fixed[c-1] + hend[c],  P_c = cumA[(c+1)*CL - 1]
__global__ __launch_bounds__(256) void scanfix_kernel(float* __restrict__ hend, const float* __restrict__ cumA) {
    int bh = blockIdx.x; int tid = threadIdx.x;
    float P[NC - 1];
#pragma unroll
    for (int c = 1; c < NC - 1; c++) P[c] = cumA[(long)bh * T + (long)(c + 1) * CL - 1];
    float* hb = hend + (long)bh * (NC - 1) * 8192;
    for (int e = tid; e < 8192; e += 256) {
        float acc = hb[e];
#pragma unroll
        for (int c = 1; c < NC - 1; c++) {
            acc = fmaf(P[c], acc, hb[(long)c * 8192 + e]);
            hb[(long)c * 8192 + e] = acc;
        }
    }
}

// ---------------------------------------------------------- SSM scan v10-C
// y[t] += cumA_t * (C_t . Hin[chunk(t)])   for chunks 1..NC-1
// grid = 128 bh x (NC-1) cm x (CL/128) tq
__global__ __launch_bounds__(256) void scancorr_kernel(const float* __restrict__ hend, const float* __restrict__ cumA,
                                                       const float* __restrict__ xbc, float* __restrict__ ys) {
    int blk = blockIdx.x;
    constexpr int TQ = CL / 128;
    int tq = blk % TQ;
    int cm = (blk / TQ) % (NC - 1);   // chunk c = cm+1
    int bh = blk / (TQ * (NC - 1));
    int b = bh >> 5, h = bh & 31;
    int tid = threadIdx.x;
    int p = tid >> 2, nq = tid & 3;
    const float* Hin = hend + ((long)bh * (NC - 1) + cm) * 8192 + p * 128 + nq * 32;
    float hreg[32];
#pragma unroll
    for (int j = 0; j < 32; j += 4) *(float4*)&hreg[j] = *(const float4*)(Hin + j);
    __shared__ float sC[8][128];
    long t0 = (long)(cm + 1) * CL + tq * 128;
    const float* cA = cumA + (long)bh * T;
    for (int tg = 0; tg < 16; tg++) {
        __syncthreads();
        {
            int tt = tg * 8 + (tid >> 5);
            int cc = (tid & 31) * 4;
            *(float4*)&sC[tid >> 5][cc] = *(const float4*)(xbc + ((long)b * T + t0 + tt) * CCH + 2176 + cc);
        }
        __syncthreads();
#pragma unroll
        for (int j = 0; j < 8; j++) {
            long t = t0 + tg * 8 + j;
            const float* Cr = &sC[j][nq * 32];
            float d = 0.f;
#pragma unroll
            for (int k = 0; k < 32; k += 4) {
                float4 cv = *(const float4*)(Cr + k);
                d += hreg[k] * cv.x + hreg[k + 1] * cv.y + hreg[k + 2] * cv.z + hreg[k + 3] * cv.w;
            }
            d += __shfl_xor(d, 1);
            d += __shfl_xor(d, 2);
            if (nq == 0) {
                float ca = cA[t];
                ys[((long)b * T + t) * DIN + h * 64 + p] += ca * d;
            }
        }
    }
}

// -------------------------------------------- rmsnorm(y_scan * silu(z)), in-place
__global__ __launch_bounds__(256) void ssmnorm_kernel(float* __restrict__ ys, const float* __restrict__ z,
                                                      const float* __restrict__ w) {
    long row = blockIdx.x; int tid = threadIdx.x;
    float* yr = ys + row * DIN;
    const float* zr = z + row * DIN;
    float v[8]; float ss = 0.f;
#pragma unroll
    for (int j = 0; j < 8; j++) {
        int c = tid * 8 + j;
        float zz = zr[c];
        float val = yr[c] * (zz * sigf(zz));
        v[j] = val; ss = fmaf(val, val, ss);
    }
    for (int off = 1; off < 64; off <<= 1) ss += __shfl_xor(ss, off);
    __shared__ float tmp[4];
    if ((tid & 63) == 0) tmp[tid >> 6] = ss;
    __syncthreads();
    float tot = tmp[0] + tmp[1] + tmp[2] + tmp[3];
    float scale = 1.f / sqrtf(tot * (1.f / (float)DIN) + 1e-5f);
#pragma unroll
    for (int j = 0; j < 8; j++) {
        int c = tid * 8 + j;
        yr[c] = v[j] * scale * w[c];
    }
}

// ------------------------------------------------------- score head (2)
__global__ void score2_kernel(const float* __restrict__ sh, const float* __restrict__ w2,
                              float* __restrict__ scores, double* __restrict__ ssum) {
    int row = blockIdx.x * 4 + (threadIdx.x >> 6);
    int lane = threadIdx.x & 63;
    const float* h = sh + (long)row * 256;
    double a = 0.0;
    for (int j = 0; j < 4; j++) a += (double)h[lane * 4 + j] * (double)w2[lane * 4 + j];
    for (int off = 1; off < 64; off <<= 1) a += __shfl_xor(a, off);
    if (lane == 0) {
        double sc = sigd(a);
        scores[row] = (float)sc;
        atomicAdd(&ssum[row >> 11], sc);
    }
}

// ------------------------------------------------ top-64 (stable argsort)
__global__ void top64_kernel(const float* __restrict__ scores, int* __restrict__ tidx, float* __restrict__ tval) {
    int b = blockIdx.x; int tid = threadIdx.x;
    __shared__ float s[T];
    __shared__ float rv[256];
    __shared__ int ri[256];
    for (int i = tid; i < T; i += 256) s[i] = scores[b * T + i];
    for (int k = 0; k < 64; k++) {
        __syncthreads();
        float best = -1e30f; int bi = 1 << 30;
        for (int i = tid; i < T; i += 256) {
            float v = s[i];
            if (v > best || (v == best && i < bi)) { best = v; bi = i; }
        }
        rv[tid] = best; ri[tid] = bi;
        __syncthreads();
        for (int off = 128; off > 0; off >>= 1) {
            if (tid < off) {
                float v2 = rv[tid + off]; int i2 = ri[tid + off];
                if (v2 > rv[tid] || (v2 == rv[tid] && i2 < ri[tid])) { rv[tid] = v2; ri[tid] = i2; }
            }
            __syncthreads();
        }
        if (tid == 0) { tidx[b * 64 + k] = ri[0]; tval[b * 64 + k] = rv[0]; s[ri[0]] = -1e30f; }
    }
}

// ---------------------------------------------------- summaries (64/b)
__global__ __launch_bounds__(256) void summ_kernel(const float* __restrict__ y, const int* __restrict__ tidx,
                                                   const float* __restrict__ wsum, float* __restrict__ summ) {
    int s = blockIdx.x & 63; int b = blockIdx.x >> 6;
    int tid = threadIdx.x;
    __shared__ float yrow[1024];
    int tok = tidx[b * 64 + s];
    long base = ((long)(b * T + tok));
    for (int i = tid; i < 1024; i += 256) yrow[i] = y[base * 1024 + i];
    __syncthreads();
    double acc = 0.0;
    const float* w = wsum + (long)tid * 1024;
    for (int kk = 0; kk < 1024; kk++) acc += (double)yrow[kk] * (double)w[kk];
    summ[((long)(b * 64 + s)) * 256 + tid] = (float)acc;
}

// -------------------------------------------------------- pool update
__global__ void pool_kernel(const float* __restrict__ pin, const float* __restrict__ prin,
                            const int* __restrict__ cin, const float* __restrict__ tval,
                            const float* __restrict__ summ, const double* __restrict__ ssum,
                            float* __restrict__ pout, float* __restrict__ prout,
                            float* __restrict__ cout, float* __restrict__ rmask) {
    int b = blockIdx.x; int tid = threadIdx.x;
    __shared__ float spri[64];
    __shared__ int scount, sact, sslot, srep, srslot;
    for (int i = tid; i < 64 * 256; i += 256) pout[(long)b * 16384 + i] = pin[(long)b * 16384 + i];
    if (tid < 64) spri[tid] = prin[b * 64 + tid];
    if (tid == 0) scount = cin[b];
    __syncthreads();
    for (int s = 0; s < 64; s++) {
        float imp = tval[b * 64 + s];
        bool has = imp > 0.5f;                       // TAU1
        if (tid == 0) {
            sact = 0;
            if (has && scount < 64) { sslot = scount; spri[scount] = imp; scount++; sact = 1; }
        }
        __syncthreads();
        if (sact) pout[((long)(b * 64 + sslot)) * 256 + tid] = summ[((long)(b * 64 + s)) * 256 + tid];
        if (tid < 64) {
            float v = spri[tid]; int idx = tid;
            for (int off = 1; off < 64; off <<= 1) {
                float v2 = __shfl_xor(v, off); int i2 = __shfl_xor(idx, off);
                if (v2 < v || (v2 == v && i2 < idx)) { v = v2; idx = i2; }
            }
            if (tid == 0) {
                srep = 0;
                if (has && scount >= 64 && imp > v) { srep = 1; srslot = idx; spri[idx] = imp; }
            }
        }
        __syncthreads();
        if (srep) pout[((long)(b * 64 + srslot)) * 256 + tid] = summ[((long)(b * 64 + s)) * 256 + tid];
        __syncthreads();
    }
    if (tid < 64) prout[b * 64 + tid] = spri[tid];
    if (tid == 0) {
        cout[b] = (float)scount;
        double mean = ssum[b] / (double)T;
        rmask[b] = (mean > 0.4 && scount > 0) ? 1.f : 0.f;
    }
}

// ------------------------------------------------------------ k,v proj
__global__ __launch_bounds__(256) void kv_kernel(const float* __restrict__ pool, const float* __restrict__ kw,
                                                 const float* __restrict__ vw, float* __restrict__ k,
                                                 float* __restrict__ v) {
    int blk = blockIdx.x; int b = blk >> 6, s = blk & 63; int tid = threadIdx.x;
    __shared__ float pr[256];
    pr[tid] = pool[((long)(b * 64 + s)) * 256 + tid];
    __syncthreads();
    float a = 0.f;
    const float* w = kw + (long)tid * 256;
    for (int j = 0; j < 256; j++) a = fmaf(pr[j], w[j], a);
    k[((long)(b * 64 + s)) * 256 + tid] = a;
    for (int m = 0; m < 4; m++) {
        int o = m * 256 + tid;
        const float* w2 = vw + (long)o * 256;
        float c = 0.f;
        for (int j = 0; j < 256; j++) c = fmaf(pr[j], w2[j], c);
        v[((long)(b * 64 + s)) * 1024 + o] = c;
    }
}

// ----------------------------------------------------- pool attention
__global__ __launch_bounds__(256) void attn_kernel(const float* __restrict__ q, const float* __restrict__ k,
                                                   const float* __restrict__ v, const float* __restrict__ cout,
                                                   float* __restrict__ concat) {
    long row = blockIdx.x;
    int b = (int)(row >> 11);
    int tid = threadIdx.x;
    int cnt = (int)cout[b];
    __shared__ float qs[256], slog[64], sp[64];
    qs[tid] = q[row * 256 + tid];
    __syncthreads();
    int s = tid >> 2, part = tid & 3;
    const float* kr = k + ((long)(b * 64 + s)) * 256 + part * 64;
    float d = 0.f;
    for (int j = 0; j < 64; j++) d = fmaf(qs[part * 64 + j], kr[j], d);
    d += __shfl_xor(d, 1); d += __shfl_xor(d, 2);
    if (part == 0) slog[s] = d * 0.0625f;
    __syncthreads();
    if (tid < 64) {
        float l = (tid < cnt) ? slog[tid] : -1e30f;
        float m = l;
        for (int off = 1; off < 64; off <<= 1) m = fmaxf(m, __shfl_xor(m, off));
        float e = (tid < cnt) ? expf(l - m) : 0.f;
        float su = e;
        for (int off = 1; off < 64; off <<= 1) su += __shfl_xor(su, off);
        sp[tid] = (cnt > 0) ? e / su : 0.f;
    }
    __syncthreads();
    float acc[4] = {0.f, 0.f, 0.f, 0.f};
    for (int s2 = 0; s2 < cnt; s2++) {
        float p = sp[s2];
        const float* vr = v + ((long)(b * 64 + s2)) * 1024 + tid;
        acc[0] = fmaf(p, vr[0], acc[0]);
        acc[1] = fmaf(p, vr[256], acc[1]);
        acc[2] = fmaf(p, vr[512], acc[2]);
        acc[3] = fmaf(p, vr[768], acc[3]);
    }
    for (int j = 0; j < 4; j++) concat[row * 2048 + 1024 + tid + j * 256] = acc[j];
}

// ===========================================================================
extern "C" void kernel_launch(void* const* d_in, const int* in_sizes, int n_in,
                              void* d_out, int out_size, void* d_ws, size_t ws_size,
                              hipStream_t stream) {
    (void)in_sizes; (void)n_in; (void)out_size;
    const float* x       = (const float*)d_in[0];
    const float* pool_in = (const float*)d_in[1];
    const float* pri_in  = (const float*)d_in[2];
    const int*   cnt_in  = (const int*)d_in[3];
    const float* norm_w  = (const float*)d_in[4];
    const float* in_w    = (const float*)d_in[5];
    const float* conv_w  = (const float*)d_in[6];
    const float* conv_b  = (const float*)d_in[7];
    const float* dt_bias = (const float*)d_in[8];
    const float* A_log   = (const float*)d_in[9];
    const float* Dp      = (const float*)d_in[10];
    const float* ssm_w   = (const float*)d_in[11];
    const float* out_w   = (const float*)d_in[12];
    const float* s_w1    = (const float*)d_in[13];
    const float* s_w2    = (const float*)d_in[14];
    const float* summ_w  = (const float*)d_in[15];
    const float* q_w     = (const float*)d_in[16];
    const float* k_w     = (const float*)d_in[17];
    const float* v_w     = (const float*)d_in[18];
    const float* gate_w  = (const float*)d_in[19];

    float* outy    = (float*)d_out;
    float* outpool = outy + (long)ROWS * D;
    float* outpri  = outpool + Bb * 64 * 256;
    float* outcnt  = outpri + Bb * 64;

    char* ws = (char*)d_ws;
    size_t cur = 0;
    auto alloc = [&](size_t bytes) { size_t o = cur; cur += (bytes + 255) / 256 * 256; return o; };

    size_t pw_in_bytes   = (size_t)2 * DPROJ * 1024 * 2;   // 17.9 MB
    size_t ra_bytes = (size_t)ROWS * CCH * 4;              // 75.5 MB >= planes 51.5

    size_t o_dt   = alloc((size_t)ROWS * NH * 4);
    size_t o_da   = alloc((size_t)ROWS * NH * 4);
    size_t o_sc   = alloc((size_t)ROWS * 4);
    size_t o_ssum = alloc(64);
    size_t o_rmk  = alloc(64);
    size_t o_tidx = alloc(Bb * 64 * 4);
    size_t o_tval = alloc(Bb * 64 * 4);
    size_t o_summ = alloc((size_t)Bb * 64 * 256 * 4);
    size_t o_k    = alloc((size_t)Bb * 64 * 256 * 4);
    size_t o_v    = alloc((size_t)Bb * 64 * 1024 * 4);
    size_t o_cumA = alloc((size_t)128 * T * 4);                // 1 MB
    size_t o_RA = alloc(ra_bytes);                 // pw_in+uplanes -> xbc -> concat+sch
    size_t o_RB = alloc((size_t)ROWS * DIN * 4);   // bufZ -> out_w/s_w1 planes -> qbuf
    size_t o_RC = alloc((size_t)ROWS * CCH * 4);   // bufX -> yscan/normed (in-place)

    if (ws_size < cur) {   // diagnostic: report ws_size in MB via absmax
        diag_kernel<<<1, 64, 0, stream>>>(outy, 1000.0f + (float)(ws_size >> 20));
        return;
    }

    float* dtb    = (float*)(ws + o_dt);
    float* dab    = (float*)(ws + o_da);
    float* scores = (float*)(ws + o_sc);
    double* ssum  = (double*)(ws + o_ssum);
    float* rmk    = (float*)(ws + o_rmk);
    int*   tidx   = (int*)(ws + o_tidx);
    float* tval   = (float*)(ws + o_tval);
    float* summ   = (float*)(ws + o_summ);
    float* kbuf   = (float*)(ws + o_k);
    float* vbuf   = (float*)(ws + o_v);
    float* cumA   = (float*)(ws + o_cumA);
    // hend (29.4 MB = 128*(NC-1)*8192 floats) lives in the DEAD outy region
    // of d_out: first written at scan (step 4), last read at scancorr (4c),
    // fully overwritten by out_proj (step 6).  outy = 33.5 MB >= 29.4 MB.
    float* hend   = outy;

    u16*  pw_in   = (u16*)(ws + o_RA);
    u16*  uplanes = (u16*)(ws + o_RA + pw_in_bytes);
    float* xbc    = (float*)(ws + o_RA);
    float* concat = (float*)(ws + o_RA);
    float* sch    = (float*)(ws + o_RA + (size_t)ROWS * DIN * 4);
    float* bufZ   = (float*)(ws + o_RB);
    u16*  pw_out  = (u16*)(ws + o_RB);
    u16*  pw_s1   = (u16*)(ws + o_RB + (size_t)16 * 1024 * 1024);
    float* qbuf   = (float*)(ws + o_RB);
    float* bufX   = (float*)(ws + o_RC);
    float* yscan  = (float*)(ws + o_RC);

    // 0. init + in_w plane split (RA is dead until conv)
    zerod_kernel<<<1, 64, 0, stream>>>(ssum, 4);
    {
        long n = (long)DPROJ * 1024;
        split2_kernel<<<(n + 255) / 256, 256, 0, stream>>>(in_w, pw_in, n);
    }
    // 1. rmsnorm(x) -> u as 2 fp16 planes (RA, behind pw_in)
    rms_x_kernel<<<ROWS, 256, 0, stream>>>(x, norm_w, uplanes, (long)ROWS * D);
    // 2. in_proj (fp16 2-plane, A+B pre-split DMA): -> bufZ, bufX, dt/dA
    gemm_f32<2, 0, true, true><<<dim3(35, 64), 256, 0, stream>>>(
        nullptr, 0, uplanes, (size_t)ROWS * D,
        nullptr, 0, pw_in, (size_t)DPROJ * 1024,
        ROWS, DPROJ, 1024,
        bufZ, bufX, dt_bias, A_log, dtb, dab);
    // 3. conv + silu (f32) -> xbc (R_A, over dead planes)
    conv_kernel<<<Bb * 32 * 36, 256, 0, stream>>>(bufX, conv_w, conv_b, xbc);
    // 4. scan v10: NC=8 chunked phase A + boundary prefix + correction
    scan_kernel<<<Bb * NH * NC * 4, 64, 0, stream>>>(xbc, dtb, dab, Dp, yscan, hend, cumA);
    scanfix_kernel<<<128, 256, 0, stream>>>(hend, cumA);
    scancorr_kernel<<<128 * (NC - 1) * (CL / 128), 256, 0, stream>>>(hend, cumA, xbc, yscan);
    // 5. ssm rmsnorm (f32, in-place over yscan); bufZ dead after this
    ssmnorm_kernel<<<ROWS, 256, 0, stream>>>(yscan, bufZ, ssm_w);
    // 5b. out_w + s_w1 plane splits into dead R_B
    {
        long n = (long)1024 * 2048;
        split2_kernel<<<(n + 255) / 256, 256, 0, stream>>>(out_w, pw_out, n);
        long n2 = (long)256 * 1024;
        split2_kernel<<<(n2 + 255) / 256, 256, 0, stream>>>(s_w1, pw_s1, n2);
    }
    // 6. out_proj (fp16 2-plane, DMA B) + residual -> outy, concat (R_A)
    gemm_f32<2, 2, true, false><<<dim3(8, 64), 256, 0, stream>>>(
        yscan, 2048, nullptr, 0,
        nullptr, 0, pw_out, (size_t)1024 * 2048,
        ROWS, 1024, 2048,
        outy, concat, x, nullptr, nullptr, nullptr);
    // 7. score1 (fp16 2-plane, DMA B, relu) -> sch
    gemm_f32<2, 1, true, false><<<dim3(2, 64), 256, 0, stream>>>(
        outy, 1024, nullptr, 0,
        nullptr, 0, pw_s1, (size_t)256 * 1024,
        ROWS, 256, 1024,
        sch, nullptr, nullptr, nullptr, nullptr, nullptr);
    // 8. score2 (f64) -> scores, ssum
    score2_kernel<<<ROWS / 4, 256, 0, stream>>>(sch, s_w2, scores, ssum);
    // 9. top-64
    top64_kernel<<<Bb, 256, 0, stream>>>(scores, tidx, tval);
    // 10. summaries (f32 y, f64 accum)
    summ_kernel<<<Bb * 64, 256, 0, stream>>>(outy, tidx, summ_w, summ);
    // 11. pool update -> d_out pool/pri/counts + rmask
    pool_kernel<<<Bb, 256, 0, stream>>>(pool_in, pri_in, cnt_in, tval, summ, ssum,
                                        outpool, outpri, outcnt, rmk);
    // 12. k, v
    kv_kernel<<<Bb * 64, 256, 0, stream>>>(outpool, k_w, v_w, kbuf, vbuf);
    // 13. q = y @ q_w^T (fp16 single-plane); qbuf overlays dead out_w planes
    gemm_f32<1, 3, false, false><<<dim3(2, 64), 256, 0, stream>>>(
        outy, 1024, nullptr, 0,
        q_w, 1024, nullptr, 0,
        ROWS, 256, 1024,
        qbuf, nullptr, nullptr, nullptr, nullptr, nullptr);
    // 14. attention -> retrieved (f32, concat second half)
    attn_kernel<<<ROWS, 256, 0, stream>>>(qbuf, kbuf, vbuf, outcnt, concat);
    // 15. gate GEMM (fp16 single-plane) + final y update
    gemm_f32<1, 4, false, false><<<dim3(8, 64), 256, 0, stream>>>(
        concat, 2048, nullptr, 0,
        gate_w, 2048, nullptr, 0,
        ROWS, 1024, 2048,
        outy, nullptr, concat, rmk, nullptr, nullptr);
}

// Round 20
// 1645.643 us; speedup vs baseline: 1.0423x; 1.0310x over previous
//
#include <hip/hip_runtime.h>

// ---------------------------------------------------------------------------
// MemMambaBlock on MI355X.  B=4 T=2048 D=1024 D_INNER=2048 D_STATE=128
// NHEADS=32 HEADDIM=64 D_CONV=4 POOL=64 SUMDIM=256 d_in_proj=4384
// R20 (tail attack): top64_kernel rewritten register-resident with shuffle
// reduce (2 barriers/selection, was 9; same tie-break total order -> bit-
// exact winner); pool_kernel merged to 2 barriers/slot (was 3).  Both
// kernels run on only 4 blocks -- serial barrier time on 4 CUs was a
// hidden ~60-100us tail.  Everything else byte-identical to R19.
// Scan v10: NC=8 chunked linear scan.  GEMM v9: fp16 2-plane + dbuf.
// ---------------------------------------------------------------------------

using u16 = unsigned short;
using f16x8 = __attribute__((ext_vector_type(8))) _Float16;
using f32x4  = __attribute__((ext_vector_type(4))) float;

#define DEV __device__ __forceinline__

#define GLOAD4(g, l)  __builtin_amdgcn_global_load_lds((const __attribute__((address_space(1))) void*)(g), (__attribute__((address_space(3))) void*)(l), 4, 0, 0)
#define GLOAD16(g, l) __builtin_amdgcn_global_load_lds((const __attribute__((address_space(1))) void*)(g), (__attribute__((address_space(3))) void*)(l), 16, 0, 0)
#define VMWAIT(N) asm volatile("s_waitcnt vmcnt(" #N ")" ::: "memory")

static constexpr int Bb = 4, T = 2048, D = 1024;
static constexpr int DIN = 2048, DST = 128, NH = 32;
static constexpr int DPROJ = 4384;          // 2*DIN + 2*DST + NH
static constexpr int CCH = 2304;            // DIN + 2*DST (conv channels)
static constexpr int ROWS = Bb * T;         // 8192
static constexpr int NC = 8, CL = 256;      // chunks x chunk length
static constexpr float RSC = 4096.f, RSCI = 1.f / 4096.f;

DEV u16 f2h_bits(float f) { union { _Float16 h; u16 u; } v; v.h = (_Float16)f; return v.u; }
DEV float h2f(u16 u) { union { _Float16 h; u16 u; } v; v.u = u; return (float)v.h; }
DEV double sigd(double x) { return 1.0 / (1.0 + exp(-x)); }
DEV float sigf(float x) { return 1.f / (1.f + expf(-x)); }
DEV int swz(int c) { return c ^ ((c >> 3) & 3); }   // involution, row-preserving

__global__ void diag_kernel(float* o, float v) { if (threadIdx.x == 0) o[0] = v; }
__global__ void zerod_kernel(double* p, int n) { if ((int)threadIdx.x < n) p[threadIdx.x] = 0.0; }

// ------------------------------------- 2-plane fp16 split (scaled residual)
__global__ void split2_kernel(const float* __restrict__ in, u16* __restrict__ out, long n) {
    long i = (long)blockIdx.x * 256 + threadIdx.x;
    if (i >= n) return;
    float v = in[i];
    u16 h = f2h_bits(v);
    float r1 = (v - h2f(h)) * RSC;
    out[i] = h;
    out[n + i] = f2h_bits(r1);
}

// ------------------------------------------- rmsnorm(x) -> 2 fp16 planes
__global__ __launch_bounds__(256) void rms_x_kernel(const float* __restrict__ x, const float* __restrict__ w,
                                                    u16* __restrict__ up, long pstride) {
    long row = blockIdx.x; int tid = threadIdx.x;
    const float* xr = x + row * D;
    float4 xv = *(const float4*)(xr + tid * 4);
    double ss = (double)xv.x * xv.x + (double)xv.y * xv.y + (double)xv.z * xv.z + (double)xv.w * xv.w;
    for (int off = 1; off < 64; off <<= 1) ss += __shfl_xor(ss, off);
    __shared__ double tmp[4];
    if ((tid & 63) == 0) tmp[tid >> 6] = ss;
    __syncthreads();
    double tot = tmp[0] + tmp[1] + tmp[2] + tmp[3];
    double scale = 1.0 / sqrt(tot / (double)D + 1e-4);
    float4 wv = *(const float4*)(w + tid * 4);
    long base = row * D + tid * 4;
    float vals[4];
    vals[0] = (float)((double)xv.x * scale * (double)wv.x);
    vals[1] = (float)((double)xv.y * scale * (double)wv.y);
    vals[2] = (float)((double)xv.z * scale * (double)wv.z);
    vals[3] = (float)((double)xv.w * scale * (double)wv.w);
#pragma unroll
    for (int j = 0; j < 4; j++) {
        float f = vals[j];
        u16 h = f2h_bits(f);
        up[base + j] = h;
        up[pstride + base + j] = f2h_bits((f - h2f(h)) * RSC);
    }
}

// ----------------------------------------------------------------- GEMM
template <int NP>
DEV void stage_one(u16* s0, u16* s1, const float* __restrict__ src, long ld,
                   int row0, int lastrow, int k0, int tid) {
    int r = tid >> 1, cb = (tid & 1) * 2;       // chunk-col base (0 or 2)
    long rg = row0 + r; if (rg > lastrow) rg = lastrow;
    const float* p = src + rg * ld + k0 + cb * 8;
    u16 h16[16], l16[16];
#pragma unroll
    for (int q = 0; q < 4; q++) {
        float4 v4 = *(const float4*)(p + q * 4);
        float vv[4] = { v4.x, v4.y, v4.z, v4.w };
#pragma unroll
        for (int j = 0; j < 4; j++) {
            float xv = vv[j];
            u16 h = f2h_bits(xv);
            h16[q * 4 + j] = h;
            if constexpr (NP == 2) l16[q * 4 + j] = f2h_bits((xv - h2f(h)) * RSC);
        }
    }
    int o0 = swz(r * 4 + cb) * 8, o1 = swz(r * 4 + cb + 1) * 8;
    *(uint4*)(s0 + o0) = *(const uint4*)(h16);
    *(uint4*)(s0 + o1) = *(const uint4*)(h16 + 8);
    if constexpr (NP == 2) {
        *(uint4*)(s1 + o0) = *(const uint4*)(l16);
        *(uint4*)(s1 + o1) = *(const uint4*)(l16 + 8);
    }
}

DEV void stage_pre_dma(u16* dst, const u16* __restrict__ src, long ld,
                       int row0, int lastrow, int k0, int wid, int lane) {
#pragma unroll
    for (int j = 0; j < 2; j++) {
        int s = wid * 128 + j * 64 + lane;
        int g = swz(s);
        int r = g >> 2, cs = g & 3;
        long rg = row0 + r; if (rg > lastrow) rg = lastrow;
        const u16* gp = src + rg * ld + k0 + cs * 8;
        GLOAD16(gp, dst + (wid * 128 + j * 64) * 8);
    }
}

#define STAGE_TILE(bb, k0_) do { \
    u16* As0_ = (bb); \
    u16* As1_ = (bb) + 4096; \
    u16* Bs0_ = (bb) + NP * 4096; \
    u16* Bs1_ = (bb) + NP * 4096 + 4096; \
    if constexpr (BP) { \
        stage_pre_dma(Bs0_, Bp, K, tN, N - 1, (k0_), wid, lane); \
        if constexpr (NP == 2) stage_pre_dma(Bs1_, Bp + bstride, K, tN, N - 1, (k0_), wid, lane); \
    } \
    if constexpr (AP) { \
        stage_pre_dma(As0_, Ap, K, tM, M - 1, (k0_), wid, lane); \
        if constexpr (NP == 2) stage_pre_dma(As1_, Ap + astride, K, tM, M - 1, (k0_), wid, lane); \
    } else { \
        stage_one<NP>(As0_, NP == 2 ? As1_ : nullptr, A, lda, tM, M - 1, (k0_), tid); \
    } \
    if constexpr (!BP) { \
        stage_one<NP>(Bs0_, NP == 2 ? Bs1_ : nullptr, B, ldb, tN, N - 1, (k0_), tid); \
    } \
} while (0)

template <int NP, int MODE, bool BP, bool AP>
__global__ __launch_bounds__(256, 2) void gemm_f32(
    const float* __restrict__ A, long lda,
    const u16* __restrict__ Ap, size_t astride,
    const float* __restrict__ B, long ldb,
    const u16* __restrict__ Bp, size_t bstride,
    int M, int N, int K,
    float* __restrict__ out0, float* __restrict__ out1,
    const float* __restrict__ aux0, const float* __restrict__ aux1,
    float* __restrict__ dtb, float* __restrict__ dab) {
    __shared__ __align__(16) u16 sm[2 * NP * 2 * 4096];   // double-buffered
    int tid = threadIdx.x, lane = tid & 63, wid = tid >> 6;
    int wr = wid >> 1, wc = wid & 1;
    int nwg = gridDim.x * gridDim.y;
    int wg = blockIdx.y * gridDim.x + blockIdx.x;
    int lin = (wg & 7) * (nwg >> 3) + (wg >> 3);
    int tM = (lin / gridDim.x) * 128, tN = (lin % gridDim.x) * 128;

    f32x4 acc1[4][4], acc2[4][4];
#pragma unroll
    for (int i = 0; i < 4; i++)
#pragma unroll
        for (int j = 0; j < 4; j++) {
            acc1[i][j] = f32x4{0.f, 0.f, 0.f, 0.f};
            if constexpr (NP == 2) acc2[i][j] = f32x4{0.f, 0.f, 0.f, 0.f};
        }

    int rA = wr * 64 + (lane & 15);
    int rB = wc * 64 + (lane & 15);
    int kc = lane >> 4;
    int oA[4], oB[4];
#pragma unroll
    for (int i = 0; i < 4; i++) {
        oA[i] = swz((rA + i * 16) * 4 + kc) * 8;
        oB[i] = swz((rB + i * 16) * 4 + kc) * 8;
    }

    int nsteps = K / 32;
    int cur = 0;
    STAGE_TILE(sm, 0);
    __syncthreads();                         // drains prologue DMA + ds_writes
    for (int kt = 0; kt < nsteps; ++kt) {
        u16* cb = sm + cur * (NP * 2 * 4096);
        if (kt + 1 < nsteps) {
            u16* nb = sm + (cur ^ 1) * (NP * 2 * 4096);
            STAGE_TILE(nb, (kt + 1) * 32);   // DMA overlaps this tile's MFMA
        }
        u16* As0 = cb; u16* As1 = cb + 4096;
        u16* Bs0 = cb + NP * 4096; u16* Bs1 = cb + NP * 4096 + 4096;
        f16x8 fa[4], fb[4];
#pragma unroll
        for (int i = 0; i < 4; i++) {
            fa[i] = *(const f16x8*)(As0 + oA[i]);
            fb[i] = *(const f16x8*)(Bs0 + oB[i]);
        }
#pragma unroll
        for (int mi = 0; mi < 4; mi++)
#pragma unroll
            for (int ni = 0; ni < 4; ni++)
                acc1[mi][ni] = __builtin_amdgcn_mfma_f32_16x16x32_f16(fa[mi], fb[ni], acc1[mi][ni], 0, 0, 0);
        if constexpr (NP == 2) {
#pragma unroll
            for (int i = 0; i < 4; i++) fb[i] = *(const f16x8*)(Bs1 + oB[i]);
#pragma unroll
            for (int mi = 0; mi < 4; mi++)
#pragma unroll
                for (int ni = 0; ni < 4; ni++)
                    acc2[mi][ni] = __builtin_amdgcn_mfma_f32_16x16x32_f16(fa[mi], fb[ni], acc2[mi][ni], 0, 0, 0);
#pragma unroll
            for (int i = 0; i < 4; i++) {
                fa[i] = *(const f16x8*)(As1 + oA[i]);
                fb[i] = *(const f16x8*)(Bs0 + oB[i]);
            }
#pragma unroll
            for (int mi = 0; mi < 4; mi++)
#pragma unroll
                for (int ni = 0; ni < 4; ni++)
                    acc2[mi][ni] = __builtin_amdgcn_mfma_f32_16x16x32_f16(fa[mi], fb[ni], acc2[mi][ni], 0, 0, 0);
        }
        if (kt + 1 < nsteps) {
            __syncthreads();                 // drains next-tile DMA (hidden under MFMA)
            cur ^= 1;
        }
    }
    int laneh = lane >> 4, lanel = lane & 15;
#pragma unroll
    for (int mi = 0; mi < 4; mi++)
#pragma unroll
        for (int ni = 0; ni < 4; ni++) {
            int col = tN + wc * 64 + ni * 16 + lanel;
            if (col >= N) continue;
#pragma unroll
            for (int r = 0; r < 4; r++) {
                long row = tM + wr * 64 + mi * 16 + laneh * 4 + r;
                float v = acc1[mi][ni][r];
                if constexpr (NP == 2) v += acc2[mi][ni][r] * RSCI;
                if constexpr (MODE == 0) {
                    if (col < 2048) out0[row * 2048 + col] = v;
                    else if (col < 4352) out1[row * 2304 + (col - 2048)] = v;
                    else {
                        int h = col - 4352;
                        double xx = (double)v + (double)aux0[h];
                        double sp = (xx > 30.0) ? xx : log1p(exp(xx));
                        double a = -exp((double)aux1[h]);
                        dtb[row * NH + h] = (float)sp;
                        dab[row * NH + h] = (float)exp(sp * a);
                    }
                } else if constexpr (MODE == 1) {
                    out0[row * 256 + col] = fmaxf(v, 0.f);
                } else if constexpr (MODE == 2) {
                    float y = aux0[row * 1024 + col] + v;
                    out0[row * 1024 + col] = y;
                    out1[row * 2048 + col] = y;
                } else if constexpr (MODE == 3) {
                    out0[row * 256 + col] = v;
                } else {
                    double g = sigd((double)v);
                    float retr = aux0[row * 2048 + 1024 + col];
                    out0[row * 1024 + col] += (float)(g * (double)retr * (double)aux1[row >> 11]);
                }
            }
        }
}

// ------------------------------------------------- depthwise causal conv4
__global__ __launch_bounds__(256) void conv_kernel(const float* __restrict__ xin, const float* __restrict__ cw,
                                                   const float* __restrict__ cb, float* __restrict__ xbc) {
    int blk = blockIdx.x;
    int ct = blk % 36; int tt = (blk / 36) % 32; int b = blk / (36 * 32);
    int c0 = ct * 64, t0 = tt * 64;
    int tid = threadIdx.x;
    __shared__ float tile[67 * 64];
    for (int i = tid; i < 67 * 64; i += 256) {
        int r = i >> 6, c = i & 63;
        int t = t0 - 3 + r;
        tile[i] = (t >= 0) ? xin[((long)(b * T + t)) * CCH + c0 + c] : 0.f;
    }
    __syncthreads();
    int c = tid & 63; int rb = (tid >> 6) * 16;
    int gc = c0 + c;
    float w0 = cw[gc * 4], w1 = cw[gc * 4 + 1], w2 = cw[gc * 4 + 2], w3 = cw[gc * 4 + 3];
    float bias = cb[gc];
    for (int j = 0; j < 16; j++) {
        int tl = rb + j;
        float a = bias + w0 * tile[tl * 64 + c] + w1 * tile[(tl + 1) * 64 + c]
                       + w2 * tile[(tl + 2) * 64 + c] + w3 * tile[(tl + 3) * 64 + c];
        xbc[((long)(b * T + t0 + tl)) * CCH + gc] = a * sigf(a);
    }
}

// ---------------------------------------------------------- SSM scan v10-A
#define SCAN_STEP(tt) do { \
    int slot_ = (tt) & 7; \
    float dtv_ = sdt[(tt)], dav_ = sda[(tt)]; \
    float xt0_ = sx[slot_][pp], xt1_ = sx[slot_][pp + 8]; \
    float dtx0_ = dtv_ * xt0_, dtx1_ = dtv_ * xt1_; \
    const float4* BP_ = (const float4*)&sbc[slot_][0]; \
    float y0a_ = 0.f, y0b_ = 0.f, y1a_ = 0.f, y1b_ = 0.f; \
    _Pragma("unroll") \
    for (int r_ = 0; r_ < 4; r_++) { \
        float4 bv_ = BP_[r_ * 8 + sub]; \
        float4 cv_ = BP_[32 + r_ * 8 + sub]; \
        hs0[r_*4+0] = fmaf(dav_, hs0[r_*4+0], dtx0_ * bv_.x); y0a_ = fmaf(hs0[r_*4+0], cv_.x, y0a_); \
        hs0[r_*4+1] = fmaf(dav_, hs0[r_*4+1], dtx0_ * bv_.y); y0b_ = fmaf(hs0[r_*4+1], cv_.y, y0b_); \
        hs0[r_*4+2] = fmaf(dav_, hs0[r_*4+2], dtx0_ * bv_.z); y0a_ = fmaf(hs0[r_*4+2], cv_.z, y0a_); \
        hs0[r_*4+3] = fmaf(dav_, hs0[r_*4+3], dtx0_ * bv_.w); y0b_ = fmaf(hs0[r_*4+3], cv_.w, y0b_); \
        hs1[r_*4+0] = fmaf(dav_, hs1[r_*4+0], dtx1_ * bv_.x); y1a_ = fmaf(hs1[r_*4+0], cv_.x, y1a_); \
        hs1[r_*4+1] = fmaf(dav_, hs1[r_*4+1], dtx1_ * bv_.y); y1b_ = fmaf(hs1[r_*4+1], cv_.y, y1b_); \
        hs1[r_*4+2] = fmaf(dav_, hs1[r_*4+2], dtx1_ * bv_.z); y1a_ = fmaf(hs1[r_*4+2], cv_.z, y1a_); \
        hs1[r_*4+3] = fmaf(dav_, hs1[r_*4+3], dtx1_ * bv_.w); y1b_ = fmaf(hs1[r_*4+3], cv_.w, y1b_); \
    } \
    float y0_ = y0a_ + y0b_, y1_ = y1a_ + y1b_; \
    y0_ += __shfl_xor(y0_, 1); y0_ += __shfl_xor(y0_, 2); y0_ += __shfl_xor(y0_, 4); \
    y1_ += __shfl_xor(y1_, 1); y1_ += __shfl_xor(y1_, 2); y1_ += __shfl_xor(y1_, 4); \
    if (sub == 0) { \
        yout[(long)(tt) * DIN] = y0_ + sDp * xt0_; \
        yout[(long)(tt) * DIN + 8] = y1_ + sDp * xt1_; \
    } \
    runA *= dav_; \
    if (wrc && l == 0) cumAp[(tt)] = runA; \
} while (0)

#define SCAN_ISSUE(s) do { \
    GLOAD16(bcsrc + (long)(s) * CCH, &sbc[(s) & 7][0]); \
    GLOAD4(xsrc + (long)(s) * CCH, &sx[(s) & 7][0]); \
} while (0)

__global__ __launch_bounds__(64) void scan_kernel(const float* __restrict__ xbc, const float* __restrict__ dtb,
                                                  const float* __restrict__ dab, const float* __restrict__ Dp,
                                                  float* __restrict__ ys, float* __restrict__ hend,
                                                  float* __restrict__ cumA) {
    int bx = blockIdx.x;
    int b = bx >> 10, h = (bx >> 5) & 31, c = (bx >> 2) & 7, q4 = bx & 3;
    int l = threadIdx.x;
    int sub = l & 7, pp = l >> 3;
    __shared__ __align__(16) float sbc[8][256];   // 8 slots x (B[128] || C[128])
    __shared__ __align__(16) float sx[8][64];     // 8 slots x x-16 (16 used)
    __shared__ float sdt[CL];
    __shared__ float sda[CL];
    long rowc = (long)b * T + (long)c * CL;        // chunk row base
    const float* bcrow = xbc + rowc * CCH + 2048;
    const float* xrow  = xbc + rowc * CCH + h * 64 + q4 * 16;
    float* yout = ys + rowc * DIN + h * 64 + q4 * 16 + pp;

    int perm = ((l >> 3) & 3) | ((l & 7) << 2) | (l & 32);
    const float* bcsrc = bcrow + perm * 4;
    const float* xsrc  = xrow + (l & 15);

    bool wrc = (q4 == 0);
    float* cumAp = cumA + ((long)(b * 32 + h)) * T + (long)c * CL;
    float runA = 1.f;

    for (int i = 0; i < CL / 64; i++) {
        GLOAD4(dtb + (rowc + i * 64 + l) * NH + h, &sdt[i * 64]);
        GLOAD4(dab + (rowc + i * 64 + l) * NH + h, &sda[i * 64]);
    }
#pragma unroll
    for (int s = 0; s < 6; s++) SCAN_ISSUE(s);

    float hs0[16], hs1[16];
#pragma unroll
    for (int j = 0; j < 16; j++) { hs0[j] = 0.f; hs1[j] = 0.f; }
    float sDp = Dp[h];

    constexpr int NI = CL / 2;    // 128 iterations, 2 steps each
    for (int i = 0; i < NI - 3; i++) {
        int s0 = 2 * i + 6;
        SCAN_ISSUE(s0);
        SCAN_ISSUE(s0 + 1);
        VMWAIT(12);
        SCAN_STEP(2 * i);
        SCAN_STEP(2 * i + 1);
    }
    { int i = NI - 3; VMWAIT(8); SCAN_STEP(2 * i); SCAN_STEP(2 * i + 1); }
    { int i = NI - 2; VMWAIT(4); SCAN_STEP(2 * i); SCAN_STEP(2 * i + 1); }
    { int i = NI - 1; VMWAIT(0); SCAN_STEP(2 * i); SCAN_STEP(2 * i + 1); }

    // chunk-end states (2 p per lane) -> hend (chunks 0..NC-2)
    if (c < NC - 1) {
        float* hp = hend + (((long)(b * 32 + h)) * (NC - 1) + c) * 8192 + (q4 * 16 + pp) * 128 + sub * 16;
#pragma unroll
        for (int j = 0; j < 16; j += 4) *(float4*)(hp + j) = *(float4*)&hs0[j];
        float* hp1 = hp + 8 * 128;
#pragma unroll
        for (int j = 0; j < 16; j += 4) *(float4*)(hp1 + j) = *(float4*)&hs1[j];
    }
}

// ---------------------------------------------------------- SSM scan v10-B
__global__ __launch_bounds__(256) void scanfix_kernel(float* __restrict__ hend, const float* __restrict__ cumA) {
    int bh = blockIdx.x; int tid = threadIdx.x;
    float P[NC - 1];
#pragma unroll
    for (int c = 1; c < NC - 1; c++) P[c] = cumA[(long)bh * T + (long)(c + 1) * CL - 1];
    float* hb = hend + (long)bh * (NC - 1) * 8192;
    for (int e = tid; e < 8192; e += 256) {
        float acc = hb[e];
#pragma unroll
        for (int c = 1; c < NC - 1; c++) {
            acc = fmaf(P[c], acc, hb[(long)c * 8192 + e]);
            hb[(long)c * 8192 + e] = acc;
        }
    }
}

// ---------------------------------------------------------- SSM scan v10-C
__global__ __launch_bounds__(256) void scancorr_kernel(const float* __restrict__ hend, const float* __restrict__ cumA,
                                                       const float* __restrict__ xbc, float* __restrict__ ys) {
    int blk = blockIdx.x;
    constexpr int TQ = CL / 128;
    int tq = blk % TQ;
    int cm = (blk / TQ) % (NC - 1);   // chunk c = cm+1
    int bh = blk / (TQ * (NC - 1));
    int b = bh >> 5, h = bh & 31;
    int tid = threadIdx.x;
    int p = tid >> 2, nq = tid & 3;
    const float* Hin = hend + ((long)bh * (NC - 1) + cm) * 8192 + p * 128 + nq * 32;
    float hreg[32];
#pragma unroll
    for (int j = 0; j < 32; j += 4) *(float4*)&hreg[j] = *(const float4*)(Hin + j);
    __shared__ float sC[8][128];
    long t0 = (long)(cm + 1) * CL + tq * 128;
    const float* cA = cumA + (long)bh * T;
    for (int tg = 0; tg < 16; tg++) {
        __syncthreads();
        {
            int tt = tg * 8 + (tid >> 5);
            int cc = (tid & 31) * 4;
            *(float4*)&sC[tid >> 5][cc] = *(const float4*)(xbc + ((long)b * T + t0 + tt) * CCH + 2176 + cc);
        }
        __syncthreads();
#pragma unroll
        for (int j = 0; j < 8; j++) {
            long t = t0 + tg * 8 + j;
            const float* Cr = &sC[j][nq * 32];
            float d = 0.f;
#pragma unroll
            for (int k = 0; k < 32; k += 4) {
                float4 cv = *(const float4*)(Cr + k);
                d += hreg[k] * cv.x + hreg[k + 1] * cv.y + hreg[k + 2] * cv.z + hreg[k + 3] * cv.w;
            }
            d += __shfl_xor(d, 1);
            d += __shfl_xor(d, 2);
            if (nq == 0) {
                float ca = cA[t];
                ys[((long)b * T + t) * DIN + h * 64 + p] += ca * d;
            }
        }
    }
}

// -------------------------------------------- rmsnorm(y_scan * silu(z)), in-place
__global__ __launch_bounds__(256) void ssmnorm_kernel(float* __restrict__ ys, const float* __restrict__ z,
                                                      const float* __restrict__ w) {
    long row = blockIdx.x; int tid = threadIdx.x;
    float* yr = ys + row * DIN;
    const float* zr = z + row * DIN;
    float v[8]; float ss = 0.f;
#pragma unroll
    for (int j = 0; j < 8; j++) {
        int c = tid * 8 + j;
        float zz = zr[c];
        float val = yr[c] * (zz * sigf(zz));
        v[j] = val; ss = fmaf(val, val, ss);
    }
    for (int off = 1; off < 64; off <<= 1) ss += __shfl_xor(ss, off);
    __shared__ float tmp[4];
    if ((tid & 63) == 0) tmp[tid >> 6] = ss;
    __syncthreads();
    float tot = tmp[0] + tmp[1] + tmp[2] + tmp[3];
    float scale = 1.f / sqrtf(tot * (1.f / (float)DIN) + 1e-5f);
#pragma unroll
    for (int j = 0; j < 8; j++) {
        int c = tid * 8 + j;
        yr[c] = v[j] * scale * w[c];
    }
}

// ------------------------------------------------------- score head (2)
__global__ void score2_kernel(const float* __restrict__ sh, const float* __restrict__ w2,
                              float* __restrict__ scores, double* __restrict__ ssum) {
    int row = blockIdx.x * 4 + (threadIdx.x >> 6);
    int lane = threadIdx.x & 63;
    const float* h = sh + (long)row * 256;
    double a = 0.0;
    for (int j = 0; j < 4; j++) a += (double)h[lane * 4 + j] * (double)w2[lane * 4 + j];
    for (int off = 1; off < 64; off <<= 1) a += __shfl_xor(a, off);
    if (lane == 0) {
        double sc = sigd(a);
        scores[row] = (float)sc;
        atomicAdd(&ssum[row >> 11], sc);
    }
}

// --------------------- top-64 (register-resident, shuffle reduce, bit-exact)
__global__ __launch_bounds__(256) void top64_kernel(const float* __restrict__ scores, int* __restrict__ tidx,
                                                    float* __restrict__ tval) {
    int b = blockIdx.x; int tid = threadIdx.x;
    int lane = tid & 63, wid = tid >> 6;
    float v[8];
#pragma unroll
    for (int j = 0; j < 8; j++) v[j] = scores[b * T + tid + j * 256];
    __shared__ float wv[4];
    __shared__ int wi[4];
    __shared__ int sbesti;
    for (int k = 0; k < 64; k++) {
        // thread-local max over 8 register values; ascending index order ->
        // strict > keeps the smallest index on ties (matches reference)
        float lv = -1e30f; int li = 1 << 30;
#pragma unroll
        for (int j = 0; j < 8; j++) {
            int ii = tid + j * 256;
            if (v[j] > lv) { lv = v[j]; li = ii; }
        }
        // wave butterfly with (max value, then min index) total order
        for (int off = 1; off < 64; off <<= 1) {
            float ov = __shfl_xor(lv, off); int oi = __shfl_xor(li, off);
            if (ov > lv || (ov == lv && oi < li)) { lv = ov; li = oi; }
        }
        if (lane == 0) { wv[wid] = lv; wi[wid] = li; }
        __syncthreads();
        if (tid == 0) {
            float bv = wv[0]; int bi = wi[0];
#pragma unroll
            for (int w = 1; w < 4; w++)
                if (wv[w] > bv || (wv[w] == bv && wi[w] < bi)) { bv = wv[w]; bi = wi[w]; }
            tidx[b * 64 + k] = bi;
            tval[b * 64 + k] = bv;
            sbesti = bi;
        }
        __syncthreads();
        int bi = sbesti;
        if ((bi & 255) == tid) {
            int jj = bi >> 8;
#pragma unroll
            for (int j = 0; j < 8; j++) if (j == jj) v[j] = -1e30f;   // static idx
        }
    }
}

// ---------------------------------------------------- summaries (64/b)
__global__ __launch_bounds__(256) void summ_kernel(const float* __restrict__ y, const int* __restrict__ tidx,
                                                   const float* __restrict__ wsum, float* __restrict__ summ) {
    int s = blockIdx.x & 63; int b = blockIdx.x >> 6;
    int tid = threadIdx.x;
    __shared__ float yrow[1024];
    int tok = tidx[b * 64 + s];
    long base = ((long)(b * T + tok));
    for (int i = tid; i < 1024; i += 256) yrow[i] = y[base * 1024 + i];
    __syncthreads();
    double acc = 0.0;
    const float* w = wsum + (long)tid * 1024;
    for (int kk = 0; kk < 1024; kk++) acc += (double)yrow[kk] * (double)w[kk];
    summ[((long)(b * 64 + s)) * 256 + tid] = (float)acc;
}

// -------------------------------------------------------- pool update
// 2 barriers/slot: A = insert decision visible; B = replace decision visible.
// All spri writes are tid0-only (wave 0); argmin runs on wave 0 (same wave,
// program-ordered after tid0's update pre-barrier-A).
__global__ void pool_kernel(const float* __restrict__ pin, const float* __restrict__ prin,
                            const int* __restrict__ cin, const float* __restrict__ tval,
                            const float* __restrict__ summ, const double* __restrict__ ssum,
                            float* __restrict__ pout, float* __restrict__ prout,
                            float* __restrict__ cout, float* __restrict__ rmask) {
    int b = blockIdx.x; int tid = threadIdx.x;
    __shared__ float spri[64];
    __shared__ int scount, sact, sslot, srep, srslot;
    for (int i = tid; i < 64 * 256; i += 256) pout[(long)b * 16384 + i] = pin[(long)b * 16384 + i];
    if (tid < 64) spri[tid] = prin[b * 64 + tid];
    if (tid == 0) scount = cin[b];
    __syncthreads();
    for (int s = 0; s < 64; s++) {
        float imp = tval[b * 64 + s];
        bool has = imp > 0.5f;                       // TAU1
        if (tid == 0) {
            sact = 0;
            if (has && scount < 64) { sslot = scount; spri[scount] = imp; scount++; sact = 1; }
        }
        __syncthreads();                             // A
        if (sact) pout[((long)(b * 64 + sslot)) * 256 + tid] = summ[((long)(b * 64 + s)) * 256 + tid];
        if (tid < 64) {
            float v = spri[tid]; int idx = tid;
            for (int off = 1; off < 64; off <<= 1) {
                float v2 = __shfl_xor(v, off); int i2 = __shfl_xor(idx, off);
                if (v2 < v || (v2 == v && i2 < idx)) { v = v2; idx = i2; }
            }
            if (tid == 0) {
                srep = 0;
                if (has && scount >= 64 && imp > v) { srep = 1; srslot = idx; spri[idx] = imp; }
            }
        }
        __syncthreads();                             // B
        if (srep) pout[((long)(b * 64 + srslot)) * 256 + tid] = summ[((long)(b * 64 + s)) * 256 + tid];
    }
    __syncthreads();
    if (tid < 64) prout[b * 64 + tid] = spri[tid];
    if (tid == 0) {
        cout[b] = (float)scount;
        double mean = ssum[b] / (double)T;
        rmask[b] = (mean > 0.4 && scount > 0) ? 1.f : 0.f;
    }
}

// ------------------------------------------------------------ k,v proj
__global__ __launch_bounds__(256) void kv_kernel(const float* __restrict__ pool, const float* __restrict__ kw,
                                                 const float* __restrict__ vw, float* __restrict__ k,
                                                 float* __restrict__ v) {
    int blk = blockIdx.x; int b = blk >> 6, s = blk & 63; int tid = threadIdx.x;
    __shared__ float pr[256];
    pr[tid] = pool[((long)(b * 64 + s)) * 256 + tid];
    __syncthreads();
    float a = 0.f;
    const float* w = kw + (long)tid * 256;
    for (int j = 0; j < 256; j++) a = fmaf(pr[j], w[j], a);
    k[((long)(b * 64 + s)) * 256 + tid] = a;
    for (int m = 0; m < 4; m++) {
        int o = m * 256 + tid;
        const float* w2 = vw + (long)o * 256;
        float c = 0.f;
        for (int j = 0; j < 256; j++) c = fmaf(pr[j], w2[j], c);
        v[((long)(b * 64 + s)) * 1024 + o] = c;
    }
}

// ----------------------------------------------------- pool attention
__global__ __launch_bounds__(256) void attn_kernel(const float* __restrict__ q, const float* __restrict__ k,
                                                   const float* __restrict__ v, const float* __restrict__ cout,
                                                   float* __restrict__ concat) {
    long row = blockIdx.x;
    int b = (int)(row >> 11);
    int tid = threadIdx.x;
    int cnt = (int)cout[b];
    __shared__ float qs[256], slog[64], sp[64];
    qs[tid] = q[row * 256 + tid];
    __syncthreads();
    int s = tid >> 2, part = tid & 3;
    const float* kr = k + ((long)(b * 64 + s)) * 256 + part * 64;
    float d = 0.f;
    for (int j = 0; j < 64; j++) d = fmaf(qs[part * 64 + j], kr[j], d);
    d += __shfl_xor(d, 1); d += __shfl_xor(d, 2);
    if (part == 0) slog[s] = d * 0.0625f;
    __syncthreads();
    if (tid < 64) {
        float l = (tid < cnt) ? slog[tid] : -1e30f;
        float m = l;
        for (int off = 1; off < 64; off <<= 1) m = fmaxf(m, __shfl_xor(m, off));
        float e = (tid < cnt) ? expf(l - m) : 0.f;
        float su = e;
        for (int off = 1; off < 64; off <<= 1) su += __shfl_xor(su, off);
        sp[tid] = (cnt > 0) ? e / su : 0.f;
    }
    __syncthreads();
    float acc[4] = {0.f, 0.f, 0.f, 0.f};
    for (int s2 = 0; s2 < cnt; s2++) {
        float p = sp[s2];
        const float* vr = v + ((long)(b * 64 + s2)) * 1024 + tid;
        acc[0] = fmaf(p, vr[0], acc[0]);
        acc[1] = fmaf(p, vr[256], acc[1]);
        acc[2] = fmaf(p, vr[512], acc[2]);
        acc[3] = fmaf(p, vr[768], acc[3]);
    }
    for (int j = 0; j < 4; j++) concat[row * 2048 + 1024 + tid + j * 256] = acc[j];
}

// ===========================================================================
extern "C" void kernel_launch(void* const* d_in, const int* in_sizes, int n_in,
                              void* d_out, int out_size, void* d_ws, size_t ws_size,
                              hipStream_t stream) {
    (void)in_sizes; (void)n_in; (void)out_size;
    const float* x       = (const float*)d_in[0];
    const float* pool_in = (const float*)d_in[1];
    const float* pri_in  = (const float*)d_in[2];
    const int*   cnt_in  = (const int*)d_in[3];
    const float* norm_w  = (const float*)d_in[4];
    const float* in_w    = (const float*)d_in[5];
    const float* conv_w  = (const float*)d_in[6];
    const float* conv_b  = (const float*)d_in[7];
    const float* dt_bias = (const float*)d_in[8];
    const float* A_log   = (const float*)d_in[9];
    const float* Dp      = (const float*)d_in[10];
    const float* ssm_w   = (const float*)d_in[11];
    const float* out_w   = (const float*)d_in[12];
    const float* s_w1    = (const float*)d_in[13];
    const float* s_w2    = (const float*)d_in[14];
    const float* summ_w  = (const float*)d_in[15];
    const float* q_w     = (const float*)d_in[16];
    const float* k_w     = (const float*)d_in[17];
    const float* v_w     = (const float*)d_in[18];
    const float* gate_w  = (const float*)d_in[19];

    float* outy    = (float*)d_out;
    float* outpool = outy + (long)ROWS * D;
    float* outpri  = outpool + Bb * 64 * 256;
    float* outcnt  = outpri + Bb * 64;

    char* ws = (char*)d_ws;
    size_t cur = 0;
    auto alloc = [&](size_t bytes) { size_t o = cur; cur += (bytes + 255) / 256 * 256; return o; };

    size_t pw_in_bytes   = (size_t)2 * DPROJ * 1024 * 2;   // 17.9 MB
    size_t ra_bytes = (size_t)ROWS * CCH * 4;              // 75.5 MB >= planes 51.5

    size_t o_dt   = alloc((size_t)ROWS * NH * 4);
    size_t o_da   = alloc((size_t)ROWS * NH * 4);
    size_t o_sc   = alloc((size_t)ROWS * 4);
    size_t o_ssum = alloc(64);
    size_t o_rmk  = alloc(64);
    size_t o_tidx = alloc(Bb * 64 * 4);
    size_t o_tval = alloc(Bb * 64 * 4);
    size_t o_summ = alloc((size_t)Bb * 64 * 256 * 4);
    size_t o_k    = alloc((size_t)Bb * 64 * 256 * 4);
    size_t o_v    = alloc((size_t)Bb * 64 * 1024 * 4);
    size_t o_cumA = alloc((size_t)128 * T * 4);                // 1 MB
    size_t o_RA = alloc(ra_bytes);                 // pw_in+uplanes -> xbc -> concat+sch
    size_t o_RB = alloc((size_t)ROWS * DIN * 4);   // bufZ -> out_w/s_w1 planes -> qbuf
    size_t o_RC = alloc((size_t)ROWS * CCH * 4);   // bufX -> yscan/normed (in-place)

    if (ws_size < cur) {   // diagnostic: report ws_size in MB via absmax
        diag_kernel<<<1, 64, 0, stream>>>(outy, 1000.0f + (float)(ws_size >> 20));
        return;
    }

    float* dtb    = (float*)(ws + o_dt);
    float* dab    = (float*)(ws + o_da);
    float* scores = (float*)(ws + o_sc);
    double* ssum  = (double*)(ws + o_ssum);
    float* rmk    = (float*)(ws + o_rmk);
    int*   tidx   = (int*)(ws + o_tidx);
    float* tval   = (float*)(ws + o_tval);
    float* summ   = (float*)(ws + o_summ);
    float* kbuf   = (float*)(ws + o_k);
    float* vbuf   = (float*)(ws + o_v);
    float* cumA   = (float*)(ws + o_cumA);
    // hend (29.4 MB) lives in the DEAD outy region of d_out (overwritten by
    // out_proj at step 6).  outy = 33.5 MB >= 29.4 MB.
    float* hend   = outy;

    u16*  pw_in   = (u16*)(ws + o_RA);
    u16*  uplanes = (u16*)(ws + o_RA + pw_in_bytes);
    float* xbc    = (float*)(ws + o_RA);
    float* concat = (float*)(ws + o_RA);
    float* sch    = (float*)(ws + o_RA + (size_t)ROWS * DIN * 4);
    float* bufZ   = (float*)(ws + o_RB);
    u16*  pw_out  = (u16*)(ws + o_RB);
    u16*  pw_s1   = (u16*)(ws + o_RB + (size_t)16 * 1024 * 1024);
    float* qbuf   = (float*)(ws + o_RB);
    float* bufX   = (float*)(ws + o_RC);
    float* yscan  = (float*)(ws + o_RC);

    // 0. init + in_w plane split (RA is dead until conv)
    zerod_kernel<<<1, 64, 0, stream>>>(ssum, 4);
    {
        long n = (long)DPROJ * 1024;
        split2_kernel<<<(n + 255) / 256, 256, 0, stream>>>(in_w, pw_in, n);
    }
    // 1. rmsnorm(x) -> u as 2 fp16 planes (RA, behind pw_in)
    rms_x_kernel<<<ROWS, 256, 0, stream>>>(x, norm_w, uplanes, (long)ROWS * D);
    // 2. in_proj (fp16 2-plane, A+B pre-split DMA): -> bufZ, bufX, dt/dA
    gemm_f32<2, 0, true, true><<<dim3(35, 64), 256, 0, stream>>>(
        nullptr, 0, uplanes, (size_t)ROWS * D,
        nullptr, 0, pw_in, (size_t)DPROJ * 1024,
        ROWS, DPROJ, 1024,
        bufZ, bufX, dt_bias, A_log, dtb, dab);
    // 3. conv + silu (f32) -> xbc (R_A, over dead planes)
    conv_kernel<<<Bb * 32 * 36, 256, 0, stream>>>(bufX, conv_w, conv_b, xbc);
    // 4. scan v10: NC=8 chunked phase A + boundary prefix + correction
    scan_kernel<<<Bb * NH * NC * 4, 64, 0, stream>>>(xbc, dtb, dab, Dp, yscan, hend, cumA);
    scanfix_kernel<<<128, 256, 0, stream>>>(hend, cumA);
    scancorr_kernel<<<128 * (NC - 1) * (CL / 128), 256, 0, stream>>>(hend, cumA, xbc, yscan);
    // 5. ssm rmsnorm (f32, in-place over yscan); bufZ dead after this
    ssmnorm_kernel<<<ROWS, 256, 0, stream>>>(yscan, bufZ, ssm_w);
    // 5b. out_w + s_w1 plane splits into dead R_B
    {
        long n = (long)1024 * 2048;
        split2_kernel<<<(n + 255) / 256, 256, 0, stream>>>(out_w, pw_out, n);
        long n2 = (long)256 * 1024;
        split2_kernel<<<(n2 + 255) / 256, 256, 0, stream>>>(s_w1, pw_s1, n2);
    }
    // 6. out_proj (fp16 2-plane, DMA B) + residual -> outy, concat (R_A)
    gemm_f32<2, 2, true, false><<<dim3(8, 64), 256, 0, stream>>>(
        yscan, 2048, nullptr, 0,
        nullptr, 0, pw_out, (size_t)1024 * 2048,
        ROWS, 1024, 2048,
        outy, concat, x, nullptr, nullptr, nullptr);
    // 7. score1 (fp16 2-plane, DMA B, relu) -> sch
    gemm_f32<2, 1, true, false><<<dim3(2, 64), 256, 0, stream>>>(
        outy, 1024, nullptr, 0,
        nullptr, 0, pw_s1, (size_t)256 * 1024,
        ROWS, 256, 1024,
        sch, nullptr, nullptr, nullptr, nullptr, nullptr);
    // 8. score2 (f64) -> scores, ssum
    score2_kernel<<<ROWS / 4, 256, 0, stream>>>(sch, s_w2, scores, ssum);
    // 9. top-64 (register-resident shuffle selection)
    top64_kernel<<<Bb, 256, 0, stream>>>(scores, tidx, tval);
    // 10. summaries (f32 y, f64 accum)
    summ_kernel<<<Bb * 64, 256, 0, stream>>>(outy, tidx, summ_w, summ);
    // 11. pool update -> d_out pool/pri/counts + rmask
    pool_kernel<<<Bb, 256, 0, stream>>>(pool_in, pri_in, cnt_in, tval, summ, ssum,
                                        outpool, outpri, outcnt, rmk);
    // 12. k, v
    kv_kernel<<<Bb * 64, 256, 0, stream>>>(outpool, k_w, v_w, kbuf, vbuf);
    // 13. q = y @ q_w^T (fp16 single-plane); qbuf overlays dead out_w planes
    gemm_f32<1, 3, false, false><<<dim3(2, 64), 256, 0, stream>>>(
        outy, 1024, nullptr, 0,
        q_w, 1024, nullptr, 0,
        ROWS, 256, 1024,
        qbuf, nullptr, nullptr, nullptr, nullptr, nullptr);
    // 14. attention -> retrieved (f32, concat second half)
    attn_kernel<<<ROWS, 256, 0, stream>>>(qbuf, kbuf, vbuf, outcnt, concat);
    // 15. gate GEMM (fp16 single-plane) + final y update
    gemm_f32<1, 4, false, false><<<dim3(8, 64), 256, 0, stream>>>(
        concat, 2048, nullptr, 0,
        gate_w, 2048, nullptr, 0,
        ROWS, 1024, 2048,
        outy, nullptr, concat, rmk, nullptr, nullptr);
}

// Round 21
// 1628.152 us; speedup vs baseline: 1.0535x; 1.0107x over previous
//
#include <hip/hip_runtime.h>

// ---------------------------------------------------------------------------
// MemMambaBlock on MI355X.  B=4 T=2048 D=1024 D_INNER=2048 D_STATE=128
// NHEADS=32 HEADDIM=64 D_CONV=4 POOL=64 SUMDIM=256 d_in_proj=4384
// R21 (polish sweep, value-preserving): float4-vectorized loads in conv /
// ssmnorm / summ / score2 (identical values & reduction order); zerod fused
// into the in_w split; out_w+s_w1 splits merged into one dual kernel.
// Scan v10: NC=8 chunked linear scan, hend in dead d_out y-region.
// GEMM v9: fp16 2-plane scaled-residual split + per-pass fragments + chunk
// swizzle + 2-phase double-buffered K-loop, (256,2).
// Pipeline history: 2946 (R2 first pass) -> 1645 (R20) -> this round.
// ---------------------------------------------------------------------------

using u16 = unsigned short;
using f16x8 = __attribute__((ext_vector_type(8))) _Float16;
using f32x4  = __attribute__((ext_vector_type(4))) float;

#define DEV __device__ __forceinline__

#define GLOAD4(g, l)  __builtin_amdgcn_global_load_lds((const __attribute__((address_space(1))) void*)(g), (__attribute__((address_space(3))) void*)(l), 4, 0, 0)
#define GLOAD16(g, l) __builtin_amdgcn_global_load_lds((const __attribute__((address_space(1))) void*)(g), (__attribute__((address_space(3))) void*)(l), 16, 0, 0)
#define VMWAIT(N) asm volatile("s_waitcnt vmcnt(" #N ")" ::: "memory")

static constexpr int Bb = 4, T = 2048, D = 1024;
static constexpr int DIN = 2048, DST = 128, NH = 32;
static constexpr int DPROJ = 4384;          // 2*DIN + 2*DST + NH
static constexpr int CCH = 2304;            // DIN + 2*DST (conv channels)
static constexpr int ROWS = Bb * T;         // 8192
static constexpr int NC = 8, CL = 256;      // chunks x chunk length
static constexpr float RSC = 4096.f, RSCI = 1.f / 4096.f;

DEV u16 f2h_bits(float f) { union { _Float16 h; u16 u; } v; v.h = (_Float16)f; return v.u; }
DEV float h2f(u16 u) { union { _Float16 h; u16 u; } v; v.u = u; return (float)v.h; }
DEV double sigd(double x) { return 1.0 / (1.0 + exp(-x)); }
DEV float sigf(float x) { return 1.f / (1.f + expf(-x)); }
DEV int swz(int c) { return c ^ ((c >> 3) & 3); }   // involution, row-preserving

__global__ void diag_kernel(float* o, float v) { if (threadIdx.x == 0) o[0] = v; }

// ---------------- 2-plane fp16 split (scaled residual) + fused ssum zero
__global__ void split2_kernel(const float* __restrict__ in, u16* __restrict__ out, long n,
                              double* __restrict__ ssum) {
    long i = (long)blockIdx.x * 256 + threadIdx.x;
    if (ssum && blockIdx.x == 0 && threadIdx.x < 4) ssum[threadIdx.x] = 0.0;
    if (i >= n) return;
    float v = in[i];
    u16 h = f2h_bits(v);
    float r1 = (v - h2f(h)) * RSC;
    out[i] = h;
    out[n + i] = f2h_bits(r1);
}

// ---------------- dual-range split (out_w then s_w1), one launch
__global__ void split2_dual_kernel(const float* __restrict__ a, u16* __restrict__ oa, long na,
                                   const float* __restrict__ b2, u16* __restrict__ ob, long nb) {
    long i = (long)blockIdx.x * 256 + threadIdx.x;
    if (i < na) {
        float v = a[i];
        u16 h = f2h_bits(v);
        oa[i] = h;
        oa[na + i] = f2h_bits((v - h2f(h)) * RSC);
    } else if (i < na + nb) {
        long j = i - na;
        float v = b2[j];
        u16 h = f2h_bits(v);
        ob[j] = h;
        ob[nb + j] = f2h_bits((v - h2f(h)) * RSC);
    }
}

// ------------------------------------------- rmsnorm(x) -> 2 fp16 planes
__global__ __launch_bounds__(256) void rms_x_kernel(const float* __restrict__ x, const float* __restrict__ w,
                                                    u16* __restrict__ up, long pstride) {
    long row = blockIdx.x; int tid = threadIdx.x;
    const float* xr = x + row * D;
    float4 xv = *(const float4*)(xr + tid * 4);
    double ss = (double)xv.x * xv.x + (double)xv.y * xv.y + (double)xv.z * xv.z + (double)xv.w * xv.w;
    for (int off = 1; off < 64; off <<= 1) ss += __shfl_xor(ss, off);
    __shared__ double tmp[4];
    if ((tid & 63) == 0) tmp[tid >> 6] = ss;
    __syncthreads();
    double tot = tmp[0] + tmp[1] + tmp[2] + tmp[3];
    double scale = 1.0 / sqrt(tot / (double)D + 1e-4);
    float4 wv = *(const float4*)(w + tid * 4);
    long base = row * D + tid * 4;
    float vals[4];
    vals[0] = (float)((double)xv.x * scale * (double)wv.x);
    vals[1] = (float)((double)xv.y * scale * (double)wv.y);
    vals[2] = (float)((double)xv.z * scale * (double)wv.z);
    vals[3] = (float)((double)xv.w * scale * (double)wv.w);
#pragma unroll
    for (int j = 0; j < 4; j++) {
        float f = vals[j];
        u16 h = f2h_bits(f);
        up[base + j] = h;
        up[pstride + base + j] = f2h_bits((f - h2f(h)) * RSC);
    }
}

// ----------------------------------------------------------------- GEMM
template <int NP>
DEV void stage_one(u16* s0, u16* s1, const float* __restrict__ src, long ld,
                   int row0, int lastrow, int k0, int tid) {
    int r = tid >> 1, cb = (tid & 1) * 2;       // chunk-col base (0 or 2)
    long rg = row0 + r; if (rg > lastrow) rg = lastrow;
    const float* p = src + rg * ld + k0 + cb * 8;
    u16 h16[16], l16[16];
#pragma unroll
    for (int q = 0; q < 4; q++) {
        float4 v4 = *(const float4*)(p + q * 4);
        float vv[4] = { v4.x, v4.y, v4.z, v4.w };
#pragma unroll
        for (int j = 0; j < 4; j++) {
            float xv = vv[j];
            u16 h = f2h_bits(xv);
            h16[q * 4 + j] = h;
            if constexpr (NP == 2) l16[q * 4 + j] = f2h_bits((xv - h2f(h)) * RSC);
        }
    }
    int o0 = swz(r * 4 + cb) * 8, o1 = swz(r * 4 + cb + 1) * 8;
    *(uint4*)(s0 + o0) = *(const uint4*)(h16);
    *(uint4*)(s0 + o1) = *(const uint4*)(h16 + 8);
    if constexpr (NP == 2) {
        *(uint4*)(s1 + o0) = *(const uint4*)(l16);
        *(uint4*)(s1 + o1) = *(const uint4*)(l16 + 8);
    }
}

DEV void stage_pre_dma(u16* dst, const u16* __restrict__ src, long ld,
                       int row0, int lastrow, int k0, int wid, int lane) {
#pragma unroll
    for (int j = 0; j < 2; j++) {
        int s = wid * 128 + j * 64 + lane;
        int g = swz(s);
        int r = g >> 2, cs = g & 3;
        long rg = row0 + r; if (rg > lastrow) rg = lastrow;
        const u16* gp = src + rg * ld + k0 + cs * 8;
        GLOAD16(gp, dst + (wid * 128 + j * 64) * 8);
    }
}

#define STAGE_TILE(bb, k0_) do { \
    u16* As0_ = (bb); \
    u16* As1_ = (bb) + 4096; \
    u16* Bs0_ = (bb) + NP * 4096; \
    u16* Bs1_ = (bb) + NP * 4096 + 4096; \
    if constexpr (BP) { \
        stage_pre_dma(Bs0_, Bp, K, tN, N - 1, (k0_), wid, lane); \
        if constexpr (NP == 2) stage_pre_dma(Bs1_, Bp + bstride, K, tN, N - 1, (k0_), wid, lane); \
    } \
    if constexpr (AP) { \
        stage_pre_dma(As0_, Ap, K, tM, M - 1, (k0_), wid, lane); \
        if constexpr (NP == 2) stage_pre_dma(As1_, Ap + astride, K, tM, M - 1, (k0_), wid, lane); \
    } else { \
        stage_one<NP>(As0_, NP == 2 ? As1_ : nullptr, A, lda, tM, M - 1, (k0_), tid); \
    } \
    if constexpr (!BP) { \
        stage_one<NP>(Bs0_, NP == 2 ? Bs1_ : nullptr, B, ldb, tN, N - 1, (k0_), tid); \
    } \
} while (0)

template <int NP, int MODE, bool BP, bool AP>
__global__ __launch_bounds__(256, 2) void gemm_f32(
    const float* __restrict__ A, long lda,
    const u16* __restrict__ Ap, size_t astride,
    const float* __restrict__ B, long ldb,
    const u16* __restrict__ Bp, size_t bstride,
    int M, int N, int K,
    float* __restrict__ out0, float* __restrict__ out1,
    const float* __restrict__ aux0, const float* __restrict__ aux1,
    float* __restrict__ dtb, float* __restrict__ dab) {
    __shared__ __align__(16) u16 sm[2 * NP * 2 * 4096];   // double-buffered
    int tid = threadIdx.x, lane = tid & 63, wid = tid >> 6;
    int wr = wid >> 1, wc = wid & 1;
    int nwg = gridDim.x * gridDim.y;
    int wg = blockIdx.y * gridDim.x + blockIdx.x;
    int lin = (wg & 7) * (nwg >> 3) + (wg >> 3);
    int tM = (lin / gridDim.x) * 128, tN = (lin % gridDim.x) * 128;

    f32x4 acc1[4][4], acc2[4][4];
#pragma unroll
    for (int i = 0; i < 4; i++)
#pragma unroll
        for (int j = 0; j < 4; j++) {
            acc1[i][j] = f32x4{0.f, 0.f, 0.f, 0.f};
            if constexpr (NP == 2) acc2[i][j] = f32x4{0.f, 0.f, 0.f, 0.f};
        }

    int rA = wr * 64 + (lane & 15);
    int rB = wc * 64 + (lane & 15);
    int kc = lane >> 4;
    int oA[4], oB[4];
#pragma unroll
    for (int i = 0; i < 4; i++) {
        oA[i] = swz((rA + i * 16) * 4 + kc) * 8;
        oB[i] = swz((rB + i * 16) * 4 + kc) * 8;
    }

    int nsteps = K / 32;
    int cur = 0;
    STAGE_TILE(sm, 0);
    __syncthreads();                         // drains prologue DMA + ds_writes
    for (int kt = 0; kt < nsteps; ++kt) {
        u16* cb = sm + cur * (NP * 2 * 4096);
        if (kt + 1 < nsteps) {
            u16* nb = sm + (cur ^ 1) * (NP * 2 * 4096);
            STAGE_TILE(nb, (kt + 1) * 32);   // DMA overlaps this tile's MFMA
        }
        u16* As0 = cb; u16* As1 = cb + 4096;
        u16* Bs0 = cb + NP * 4096; u16* Bs1 = cb + NP * 4096 + 4096;
        f16x8 fa[4], fb[4];
#pragma unroll
        for (int i = 0; i < 4; i++) {
            fa[i] = *(const f16x8*)(As0 + oA[i]);
            fb[i] = *(const f16x8*)(Bs0 + oB[i]);
        }
#pragma unroll
        for (int mi = 0; mi < 4; mi++)
#pragma unroll
            for (int ni = 0; ni < 4; ni++)
                acc1[mi][ni] = __builtin_amdgcn_mfma_f32_16x16x32_f16(fa[mi], fb[ni], acc1[mi][ni], 0, 0, 0);
        if constexpr (NP == 2) {
#pragma unroll
            for (int i = 0; i < 4; i++) fb[i] = *(const f16x8*)(Bs1 + oB[i]);
#pragma unroll
            for (int mi = 0; mi < 4; mi++)
#pragma unroll
                for (int ni = 0; ni < 4; ni++)
                    acc2[mi][ni] = __builtin_amdgcn_mfma_f32_16x16x32_f16(fa[mi], fb[ni], acc2[mi][ni], 0, 0, 0);
#pragma unroll
            for (int i = 0; i < 4; i++) {
                fa[i] = *(const f16x8*)(As1 + oA[i]);
                fb[i] = *(const f16x8*)(Bs0 + oB[i]);
            }
#pragma unroll
            for (int mi = 0; mi < 4; mi++)
#pragma unroll
                for (int ni = 0; ni < 4; ni++)
                    acc2[mi][ni] = __builtin_amdgcn_mfma_f32_16x16x32_f16(fa[mi], fb[ni], acc2[mi][ni], 0, 0, 0);
        }
        if (kt + 1 < nsteps) {
            __syncthreads();                 // drains next-tile DMA (hidden under MFMA)
            cur ^= 1;
        }
    }
    int laneh = lane >> 4, lanel = lane & 15;
#pragma unroll
    for (int mi = 0; mi < 4; mi++)
#pragma unroll
        for (int ni = 0; ni < 4; ni++) {
            int col = tN + wc * 64 + ni * 16 + lanel;
            if (col >= N) continue;
#pragma unroll
            for (int r = 0; r < 4; r++) {
                long row = tM + wr * 64 + mi * 16 + laneh * 4 + r;
                float v = acc1[mi][ni][r];
                if constexpr (NP == 2) v += acc2[mi][ni][r] * RSCI;
                if constexpr (MODE == 0) {
                    if (col < 2048) out0[row * 2048 + col] = v;
                    else if (col < 4352) out1[row * 2304 + (col - 2048)] = v;
                    else {
                        int h = col - 4352;
                        double xx = (double)v + (double)aux0[h];
                        double sp = (xx > 30.0) ? xx : log1p(exp(xx));
                        double a = -exp((double)aux1[h]);
                        dtb[row * NH + h] = (float)sp;
                        dab[row * NH + h] = (float)exp(sp * a);
                    }
                } else if constexpr (MODE == 1) {
                    out0[row * 256 + col] = fmaxf(v, 0.f);
                } else if constexpr (MODE == 2) {
                    float y = aux0[row * 1024 + col] + v;
                    out0[row * 1024 + col] = y;
                    out1[row * 2048 + col] = y;
                } else if constexpr (MODE == 3) {
                    out0[row * 256 + col] = v;
                } else {
                    double g = sigd((double)v);
                    float retr = aux0[row * 2048 + 1024 + col];
                    out0[row * 1024 + col] += (float)(g * (double)retr * (double)aux1[row >> 11]);
                }
            }
        }
}

// ------------------------------------------------- depthwise causal conv4
__global__ __launch_bounds__(256) void conv_kernel(const float* __restrict__ xin, const float* __restrict__ cw,
                                                   const float* __restrict__ cb, float* __restrict__ xbc) {
    int blk = blockIdx.x;
    int ct = blk % 36; int tt = (blk / 36) % 32; int b = blk / (36 * 32);
    int c0 = ct * 64, t0 = tt * 64;
    int tid = threadIdx.x;
    __shared__ float tile[67 * 64];
    // vectorized tile load: 67 rows x 16 float4 each
    for (int i = tid; i < 67 * 16; i += 256) {
        int r = i >> 4, c4 = i & 15;
        int t = t0 - 3 + r;
        float4 v = (t >= 0) ? *(const float4*)(xin + ((long)(b * T + t)) * CCH + c0 + c4 * 4)
                            : float4{0.f, 0.f, 0.f, 0.f};
        *(float4*)&tile[r * 64 + c4 * 4] = v;
    }
    __syncthreads();
    int c = tid & 63; int rb = (tid >> 6) * 16;
    int gc = c0 + c;
    float w0 = cw[gc * 4], w1 = cw[gc * 4 + 1], w2 = cw[gc * 4 + 2], w3 = cw[gc * 4 + 3];
    float bias = cb[gc];
    for (int j = 0; j < 16; j++) {
        int tl = rb + j;
        float a = bias + w0 * tile[tl * 64 + c] + w1 * tile[(tl + 1) * 64 + c]
                       + w2 * tile[(tl + 2) * 64 + c] + w3 * tile[(tl + 3) * 64 + c];
        xbc[((long)(b * T + t0 + tl)) * CCH + gc] = a * sigf(a);
    }
}

// ---------------------------------------------------------- SSM scan v10-A
#define SCAN_STEP(tt) do { \
    int slot_ = (tt) & 7; \
    float dtv_ = sdt[(tt)], dav_ = sda[(tt)]; \
    float xt0_ = sx[slot_][pp], xt1_ = sx[slot_][pp + 8]; \
    float dtx0_ = dtv_ * xt0_, dtx1_ = dtv_ * xt1_; \
    const float4* BP_ = (const float4*)&sbc[slot_][0]; \
    float y0a_ = 0.f, y0b_ = 0.f, y1a_ = 0.f, y1b_ = 0.f; \
    _Pragma("unroll") \
    for (int r_ = 0; r_ < 4; r_++) { \
        float4 bv_ = BP_[r_ * 8 + sub]; \
        float4 cv_ = BP_[32 + r_ * 8 + sub]; \
        hs0[r_*4+0] = fmaf(dav_, hs0[r_*4+0], dtx0_ * bv_.x); y0a_ = fmaf(hs0[r_*4+0], cv_.x, y0a_); \
        hs0[r_*4+1] = fmaf(dav_, hs0[r_*4+1], dtx0_ * bv_.y); y0b_ = fmaf(hs0[r_*4+1], cv_.y, y0b_); \
        hs0[r_*4+2] = fmaf(dav_, hs0[r_*4+2], dtx0_ * bv_.z); y0a_ = fmaf(hs0[r_*4+2], cv_.z, y0a_); \
        hs0[r_*4+3] = fmaf(dav_, hs0[r_*4+3], dtx0_ * bv_.w); y0b_ = fmaf(hs0[r_*4+3], cv_.w, y0b_); \
        hs1[r_*4+0] = fmaf(dav_, hs1[r_*4+0], dtx1_ * bv_.x); y1a_ = fmaf(hs1[r_*4+0], cv_.x, y1a_); \
        hs1[r_*4+1] = fmaf(dav_, hs1[r_*4+1], dtx1_ * bv_.y); y1b_ = fmaf(hs1[r_*4+1], cv_.y, y1b_); \
        hs1[r_*4+2] = fmaf(dav_, hs1[r_*4+2], dtx1_ * bv_.z); y1a_ = fmaf(hs1[r_*4+2], cv_.z, y1a_); \
        hs1[r_*4+3] = fmaf(dav_, hs1[r_*4+3], dtx1_ * bv_.w); y1b_ = fmaf(hs1[r_*4+3], cv_.w, y1b_); \
    } \
    float y0_ = y0a_ + y0b_, y1_ = y1a_ + y1b_; \
    y0_ += __shfl_xor(y0_, 1); y0_ += __shfl_xor(y0_, 2); y0_ += __shfl_xor(y0_, 4); \
    y1_ += __shfl_xor(y1_, 1); y1_ += __shfl_xor(y1_, 2); y1_ += __shfl_xor(y1_, 4); \
    if (sub == 0) { \
        yout[(long)(tt) * DIN] = y0_ + sDp * xt0_; \
        yout[(long)(tt) * DIN + 8] = y1_ + sDp * xt1_; \
    } \
    runA *= dav_; \
    if (wrc && l == 0) cumAp[(tt)] = runA; \
} while (0)

#define SCAN_ISSUE(s) do { \
    GLOAD16(bcsrc + (long)(s) * CCH, &sbc[(s) & 7][0]); \
    GLOAD4(xsrc + (long)(s) * CCH, &sx[(s) & 7][0]); \
} while (0)

__global__ __launch_bounds__(64) void scan_kernel(const float* __restrict__ xbc, const float* __restrict__ dtb,
                                                  const float* __restrict__ dab, const float* __restrict__ Dp,
                                                  float* __restrict__ ys, float* __restrict__ hend,
                                                  float* __restrict__ cumA) {
    int bx = blockIdx.x;
    int b = bx >> 10, h = (bx >> 5) & 31, c = (bx >> 2) & 7, q4 = bx & 3;
    int l = threadIdx.x;
    int sub = l & 7, pp = l >> 3;
    __shared__ __align__(16) float sbc[8][256];   // 8 slots x (B[128] || C[128])
    __shared__ __align__(16) float sx[8][64];     // 8 slots x x-16 (16 used)
    __shared__ float sdt[CL];
    __shared__ float sda[CL];
    long rowc = (long)b * T + (long)c * CL;        // chunk row base
    const float* bcrow = xbc + rowc * CCH + 2048;
    const float* xrow  = xbc + rowc * CCH + h * 64 + q4 * 16;
    float* yout = ys + rowc * DIN + h * 64 + q4 * 16 + pp;

    int perm = ((l >> 3) & 3) | ((l & 7) << 2) | (l & 32);
    const float* bcsrc = bcrow + perm * 4;
    const float* xsrc  = xrow + (l & 15);

    bool wrc = (q4 == 0);
    float* cumAp = cumA + ((long)(b * 32 + h)) * T + (long)c * CL;
    float runA = 1.f;

    for (int i = 0; i < CL / 64; i++) {
        GLOAD4(dtb + (rowc + i * 64 + l) * NH + h, &sdt[i * 64]);
        GLOAD4(dab + (rowc + i * 64 + l) * NH + h, &sda[i * 64]);
    }
#pragma unroll
    for (int s = 0; s < 6; s++) SCAN_ISSUE(s);

    float hs0[16], hs1[16];
#pragma unroll
    for (int j = 0; j < 16; j++) { hs0[j] = 0.f; hs1[j] = 0.f; }
    float sDp = Dp[h];

    constexpr int NI = CL / 2;    // 128 iterations, 2 steps each
    for (int i = 0; i < NI - 3; i++) {
        int s0 = 2 * i + 6;
        SCAN_ISSUE(s0);
        SCAN_ISSUE(s0 + 1);
        VMWAIT(12);
        SCAN_STEP(2 * i);
        SCAN_STEP(2 * i + 1);
    }
    { int i = NI - 3; VMWAIT(8); SCAN_STEP(2 * i); SCAN_STEP(2 * i + 1); }
    { int i = NI - 2; VMWAIT(4); SCAN_STEP(2 * i); SCAN_STEP(2 * i + 1); }
    { int i = NI - 1; VMWAIT(0); SCAN_STEP(2 * i); SCAN_STEP(2 * i + 1); }

    // chunk-end states (2 p per lane) -> hend (chunks 0..NC-2)
    if (c < NC - 1) {
        float* hp = hend + (((long)(b * 32 + h)) * (NC - 1) + c) * 8192 + (q4 * 16 + pp) * 128 + sub * 16;
#pragma unroll
        for (int j = 0; j < 16; j += 4) *(float4*)(hp + j) = *(float4*)&hs0[j];
        float* hp1 = hp + 8 * 128;
#pragma unroll
        for (int j = 0; j < 16; j += 4) *(float4*)(hp1 + j) = *(float4*)&hs1[j];
    }
}

// ---------------------------------------------------------- SSM scan v10-B
__global__ __launch_bounds__(256) void scanfix_kernel(float* __restrict__ hend, const float* __restrict__ cumA) {
    int bh = blockIdx.x; int tid = threadIdx.x;
    float P[NC - 1];
#pragma unroll
    for (int c = 1; c < NC - 1; c++) P[c] = cumA[(long)bh * T + (long)(c + 1) * CL - 1];
    float* hb = hend + (long)bh * (NC - 1) * 8192;
    for (int e = tid; e < 8192; e += 256) {
        float acc = hb[e];
#pragma unroll
        for (int c = 1; c < NC - 1; c++) {
            acc = fmaf(P[c], acc, hb[(long)c * 8192 + e]);
            hb[(long)c * 8192 + e] = acc;
        }
    }
}

// ---------------------------------------------------------- SSM scan v10-C
__global__ __launch_bounds__(256) void scancorr_kernel(const float* __restrict__ hend, const float* __restrict__ cumA,
                                                       const float* __restrict__ xbc, float* __restrict__ ys) {
    int blk = blockIdx.x;
    constexpr int TQ = CL / 128;
    int tq = blk % TQ;
    int cm = (blk / TQ) % (NC - 1);   // chunk c = cm+1
    int bh = blk / (TQ * (NC - 1));
    int b = bh >> 5, h = bh & 31;
    int tid = threadIdx.x;
    int p = tid >> 2, nq = tid & 3;
    const float* Hin = hend + ((long)bh * (NC - 1) + cm) * 8192 + p * 128 + nq * 32;
    float hreg[32];
#pragma unroll
    for (int j = 0; j < 32; j += 4) *(float4*)&hreg[j] = *(const float4*)(Hin + j);
    __shared__ float sC[8][128];
    long t0 = (long)(cm + 1) * CL + tq * 128;
    const float* cA = cumA + (long)bh * T;
    for (int tg = 0; tg < 16; tg++) {
        __syncthreads();
        {
            int tt = tg * 8 + (tid >> 5);
            int cc = (tid & 31) * 4;
            *(float4*)&sC[tid >> 5][cc] = *(const float4*)(xbc + ((long)b * T + t0 + tt) * CCH + 2176 + cc);
        }
        __syncthreads();
#pragma unroll
        for (int j = 0; j < 8; j++) {
            long t = t0 + tg * 8 + j;
            const float* Cr = &sC[j][nq * 32];
            float d = 0.f;
#pragma unroll
            for (int k = 0; k < 32; k += 4) {
                float4 cv = *(const float4*)(Cr + k);
                d += hreg[k] * cv.x + hreg[k + 1] * cv.y + hreg[k + 2] * cv.z + hreg[k + 3] * cv.w;
            }
            d += __shfl_xor(d, 1);
            d += __shfl_xor(d, 2);
            if (nq == 0) {
                float ca = cA[t];
                ys[((long)b * T + t) * DIN + h * 64 + p] += ca * d;
            }
        }
    }
}

// -------------------------------------------- rmsnorm(y_scan * silu(z)), in-place
__global__ __launch_bounds__(256) void ssmnorm_kernel(float* __restrict__ ys, const float* __restrict__ z,
                                                      const float* __restrict__ w) {
    long row = blockIdx.x; int tid = threadIdx.x;
    float* yr = ys + row * DIN;
    const float* zr = z + row * DIN;
    float4 yv0 = *(const float4*)(yr + tid * 8);
    float4 yv1 = *(const float4*)(yr + tid * 8 + 4);
    float4 zv0 = *(const float4*)(zr + tid * 8);
    float4 zv1 = *(const float4*)(zr + tid * 8 + 4);
    float yv[8] = { yv0.x, yv0.y, yv0.z, yv0.w, yv1.x, yv1.y, yv1.z, yv1.w };
    float zv[8] = { zv0.x, zv0.y, zv0.z, zv0.w, zv1.x, zv1.y, zv1.z, zv1.w };
    float v[8]; float ss = 0.f;
#pragma unroll
    for (int j = 0; j < 8; j++) {
        float zz = zv[j];
        float val = yv[j] * (zz * sigf(zz));
        v[j] = val; ss = fmaf(val, val, ss);
    }
    for (int off = 1; off < 64; off <<= 1) ss += __shfl_xor(ss, off);
    __shared__ float tmp[4];
    if ((tid & 63) == 0) tmp[tid >> 6] = ss;
    __syncthreads();
    float tot = tmp[0] + tmp[1] + tmp[2] + tmp[3];
    float scale = 1.f / sqrtf(tot * (1.f / (float)DIN) + 1e-5f);
    float4 wv0 = *(const float4*)(w + tid * 8);
    float4 wv1 = *(const float4*)(w + tid * 8 + 4);
    float wv[8] = { wv0.x, wv0.y, wv0.z, wv0.w, wv1.x, wv1.y, wv1.z, wv1.w };
    float o[8];
#pragma unroll
    for (int j = 0; j < 8; j++) o[j] = v[j] * scale * wv[j];
    *(float4*)(yr + tid * 8)     = float4{ o[0], o[1], o[2], o[3] };
    *(float4*)(yr + tid * 8 + 4) = float4{ o[4], o[5], o[6], o[7] };
}

// ------------------------------------------------------- score head (2)
__global__ void score2_kernel(const float* __restrict__ sh, const float* __restrict__ w2,
                              float* __restrict__ scores, double* __restrict__ ssum) {
    int row = blockIdx.x * 4 + (threadIdx.x >> 6);
    int lane = threadIdx.x & 63;
    float4 hv = *(const float4*)(sh + (long)row * 256 + lane * 4);
    float4 wv = *(const float4*)(w2 + lane * 4);
    double a = (double)hv.x * (double)wv.x;
    a += (double)hv.y * (double)wv.y;
    a += (double)hv.z * (double)wv.z;
    a += (double)hv.w * (double)wv.w;
    for (int off = 1; off < 64; off <<= 1) a += __shfl_xor(a, off);
    if (lane == 0) {
        double sc = sigd(a);
        scores[row] = (float)sc;
        atomicAdd(&ssum[row >> 11], sc);
    }
}

// --------------------- top-64 (register-resident, shuffle reduce, bit-exact)
__global__ __launch_bounds__(256) void top64_kernel(const float* __restrict__ scores, int* __restrict__ tidx,
                                                    float* __restrict__ tval) {
    int b = blockIdx.x; int tid = threadIdx.x;
    int lane = tid & 63, wid = tid >> 6;
    float v[8];
#pragma unroll
    for (int j = 0; j < 8; j++) v[j] = scores[b * T + tid + j * 256];
    __shared__ float wv[4];
    __shared__ int wi[4];
    __shared__ int sbesti;
    for (int k = 0; k < 64; k++) {
        float lv = -1e30f; int li = 1 << 30;
#pragma unroll
        for (int j = 0; j < 8; j++) {
            int ii = tid + j * 256;
            if (v[j] > lv) { lv = v[j]; li = ii; }
        }
        for (int off = 1; off < 64; off <<= 1) {
            float ov = __shfl_xor(lv, off); int oi = __shfl_xor(li, off);
            if (ov > lv || (ov == lv && oi < li)) { lv = ov; li = oi; }
        }
        if (lane == 0) { wv[wid] = lv; wi[wid] = li; }
        __syncthreads();
        if (tid == 0) {
            float bv = wv[0]; int bi = wi[0];
#pragma unroll
            for (int w = 1; w < 4; w++)
                if (wv[w] > bv || (wv[w] == bv && wi[w] < bi)) { bv = wv[w]; bi = wi[w]; }
            tidx[b * 64 + k] = bi;
            tval[b * 64 + k] = bv;
            sbesti = bi;
        }
        __syncthreads();
        int bi = sbesti;
        if ((bi & 255) == tid) {
            int jj = bi >> 8;
#pragma unroll
            for (int j = 0; j < 8; j++) if (j == jj) v[j] = -1e30f;
        }
    }
}

// ---------------------------------------------------- summaries (64/b)
__global__ __launch_bounds__(256) void summ_kernel(const float* __restrict__ y, const int* __restrict__ tidx,
                                                   const float* __restrict__ wsum, float* __restrict__ summ) {
    int s = blockIdx.x & 63; int b = blockIdx.x >> 6;
    int tid = threadIdx.x;
    __shared__ float yrow[1024];
    int tok = tidx[b * 64 + s];
    long base = ((long)(b * T + tok));
    {
        float4 vv = *(const float4*)(y + base * 1024 + tid * 4);
        *(float4*)&yrow[tid * 4] = vv;
    }
    __syncthreads();
    double acc = 0.0;
    const float* w = wsum + (long)tid * 1024;
    for (int kk = 0; kk < 1024; kk += 4) {
        float4 wv = *(const float4*)(w + kk);
        acc += (double)yrow[kk] * (double)wv.x;
        acc += (double)yrow[kk + 1] * (double)wv.y;
        acc += (double)yrow[kk + 2] * (double)wv.z;
        acc += (double)yrow[kk + 3] * (double)wv.w;
    }
    summ[((long)(b * 64 + s)) * 256 + tid] = (float)acc;
}

// -------------------------------------------------------- pool update
__global__ void pool_kernel(const float* __restrict__ pin, const float* __restrict__ prin,
                            const int* __restrict__ cin, const float* __restrict__ tval,
                            const float* __restrict__ summ, const double* __restrict__ ssum,
                            float* __restrict__ pout, float* __restrict__ prout,
                            float* __restrict__ cout, float* __restrict__ rmask) {
    int b = blockIdx.x; int tid = threadIdx.x;
    __shared__ float spri[64];
    __shared__ int scount, sact, sslot, srep, srslot;
    for (int i = tid; i < 64 * 256; i += 256) pout[(long)b * 16384 + i] = pin[(long)b * 16384 + i];
    if (tid < 64) spri[tid] = prin[b * 64 + tid];
    if (tid == 0) scount = cin[b];
    __syncthreads();
    for (int s = 0; s < 64; s++) {
        float imp = tval[b * 64 + s];
        bool has = imp > 0.5f;                       // TAU1
        if (tid == 0) {
            sact = 0;
            if (has && scount < 64) { sslot = scount; spri[scount] = imp; scount++; sact = 1; }
        }
        __syncthreads();                             // A
        if (sact) pout[((long)(b * 64 + sslot)) * 256 + tid] = summ[((long)(b * 64 + s)) * 256 + tid];
        if (tid < 64) {
            float v = spri[tid]; int idx = tid;
            for (int off = 1; off < 64; off <<= 1) {
                float v2 = __shfl_xor(v, off); int i2 = __shfl_xor(idx, off);
                if (v2 < v || (v2 == v && i2 < idx)) { v = v2; idx = i2; }
            }
            if (tid == 0) {
                srep = 0;
                if (has && scount >= 64 && imp > v) { srep = 1; srslot = idx; spri[idx] = imp; }
            }
        }
        __syncthreads();                             // B
        if (srep) pout[((long)(b * 64 + srslot)) * 256 + tid] = summ[((long)(b * 64 + s)) * 256 + tid];
    }
    __syncthreads();
    if (tid < 64) prout[b * 64 + tid] = spri[tid];
    if (tid == 0) {
        cout[b] = (float)scount;
        double mean = ssum[b] / (double)T;
        rmask[b] = (mean > 0.4 && scount > 0) ? 1.f : 0.f;
    }
}

// ------------------------------------------------------------ k,v proj
__global__ __launch_bounds__(256) void kv_kernel(const float* __restrict__ pool, const float* __restrict__ kw,
                                                 const float* __restrict__ vw, float* __restrict__ k,
                                                 float* __restrict__ v) {
    int blk = blockIdx.x; int b = blk >> 6, s = blk & 63; int tid = threadIdx.x;
    __shared__ float pr[256];
    pr[tid] = pool[((long)(b * 64 + s)) * 256 + tid];
    __syncthreads();
    float a = 0.f;
    const float* w = kw + (long)tid * 256;
    for (int j = 0; j < 256; j++) a = fmaf(pr[j], w[j], a);
    k[((long)(b * 64 + s)) * 256 + tid] = a;
    for (int m = 0; m < 4; m++) {
        int o = m * 256 + tid;
        const float* w2 = vw + (long)o * 256;
        float c = 0.f;
        for (int j = 0; j < 256; j++) c = fmaf(pr[j], w2[j], c);
        v[((long)(b * 64 + s)) * 1024 + o] = c;
    }
}

// ----------------------------------------------------- pool attention
__global__ __launch_bounds__(256) void attn_kernel(const float* __restrict__ q, const float* __restrict__ k,
                                                   const float* __restrict__ v, const float* __restrict__ cout,
                                                   float* __restrict__ concat) {
    long row = blockIdx.x;
    int b = (int)(row >> 11);
    int tid = threadIdx.x;
    int cnt = (int)cout[b];
    __shared__ float qs[256], slog[64], sp[64];
    qs[tid] = q[row * 256 + tid];
    __syncthreads();
    int s = tid >> 2, part = tid & 3;
    const float* kr = k + ((long)(b * 64 + s)) * 256 + part * 64;
    float d = 0.f;
    for (int j = 0; j < 64; j++) d = fmaf(qs[part * 64 + j], kr[j], d);
    d += __shfl_xor(d, 1); d += __shfl_xor(d, 2);
    if (part == 0) slog[s] = d * 0.0625f;
    __syncthreads();
    if (tid < 64) {
        float l = (tid < cnt) ? slog[tid] : -1e30f;
        float m = l;
        for (int off = 1; off < 64; off <<= 1) m = fmaxf(m, __shfl_xor(m, off));
        float e = (tid < cnt) ? expf(l - m) : 0.f;
        float su = e;
        for (int off = 1; off < 64; off <<= 1) su += __shfl_xor(su, off);
        sp[tid] = (cnt > 0) ? e / su : 0.f;
    }
    __syncthreads();
    float acc[4] = {0.f, 0.f, 0.f, 0.f};
    for (int s2 = 0; s2 < cnt; s2++) {
        float p = sp[s2];
        const float* vr = v + ((long)(b * 64 + s2)) * 1024 + tid;
        acc[0] = fmaf(p, vr[0], acc[0]);
        acc[1] = fmaf(p, vr[256], acc[1]);
        acc[2] = fmaf(p, vr[512], acc[2]);
        acc[3] = fmaf(p, vr[768], acc[3]);
    }
    for (int j = 0; j < 4; j++) concat[row * 2048 + 1024 + tid + j * 256] = acc[j];
}

// ===========================================================================
extern "C" void kernel_launch(void* const* d_in, const int* in_sizes, int n_in,
                              void* d_out, int out_size, void* d_ws, size_t ws_size,
                              hipStream_t stream) {
    (void)in_sizes; (void)n_in; (void)out_size;
    const float* x       = (const float*)d_in[0];
    const float* pool_in = (const float*)d_in[1];
    const float* pri_in  = (const float*)d_in[2];
    const int*   cnt_in  = (const int*)d_in[3];
    const float* norm_w  = (const float*)d_in[4];
    const float* in_w    = (const float*)d_in[5];
    const float* conv_w  = (const float*)d_in[6];
    const float* conv_b  = (const float*)d_in[7];
    const float* dt_bias = (const float*)d_in[8];
    const float* A_log   = (const float*)d_in[9];
    const float* Dp      = (const float*)d_in[10];
    const float* ssm_w   = (const float*)d_in[11];
    const float* out_w   = (const float*)d_in[12];
    const float* s_w1    = (const float*)d_in[13];
    const float* s_w2    = (const float*)d_in[14];
    const float* summ_w  = (const float*)d_in[15];
    const float* q_w     = (const float*)d_in[16];
    const float* k_w     = (const float*)d_in[17];
    const float* v_w     = (const float*)d_in[18];
    const float* gate_w  = (const float*)d_in[19];

    float* outy    = (float*)d_out;
    float* outpool = outy + (long)ROWS * D;
    float* outpri  = outpool + Bb * 64 * 256;
    float* outcnt  = outpri + Bb * 64;

    char* ws = (char*)d_ws;
    size_t cur = 0;
    auto alloc = [&](size_t bytes) { size_t o = cur; cur += (bytes + 255) / 256 * 256; return o; };

    size_t pw_in_bytes   = (size_t)2 * DPROJ * 1024 * 2;   // 17.9 MB
    size_t ra_bytes = (size_t)ROWS * CCH * 4;              // 75.5 MB >= planes 51.5

    size_t o_dt   = alloc((size_t)ROWS * NH * 4);
    size_t o_da   = alloc((size_t)ROWS * NH * 4);
    size_t o_sc   = alloc((size_t)ROWS * 4);
    size_t o_ssum = alloc(64);
    size_t o_rmk  = alloc(64);
    size_t o_tidx = alloc(Bb * 64 * 4);
    size_t o_tval = alloc(Bb * 64 * 4);
    size_t o_summ = alloc((size_t)Bb * 64 * 256 * 4);
    size_t o_k    = alloc((size_t)Bb * 64 * 256 * 4);
    size_t o_v    = alloc((size_t)Bb * 64 * 1024 * 4);
    size_t o_cumA = alloc((size_t)128 * T * 4);                // 1 MB
    size_t o_RA = alloc(ra_bytes);                 // pw_in+uplanes -> xbc -> concat+sch
    size_t o_RB = alloc((size_t)ROWS * DIN * 4);   // bufZ -> out_w/s_w1 planes -> qbuf
    size_t o_RC = alloc((size_t)ROWS * CCH * 4);   // bufX -> yscan/normed (in-place)

    if (ws_size < cur) {   // diagnostic: report ws_size in MB via absmax
        diag_kernel<<<1, 64, 0, stream>>>(outy, 1000.0f + (float)(ws_size >> 20));
        return;
    }

    float* dtb    = (float*)(ws + o_dt);
    float* dab    = (float*)(ws + o_da);
    float* scores = (float*)(ws + o_sc);
    double* ssum  = (double*)(ws + o_ssum);
    float* rmk    = (float*)(ws + o_rmk);
    int*   tidx   = (int*)(ws + o_tidx);
    float* tval   = (float*)(ws + o_tval);
    float* summ   = (float*)(ws + o_summ);
    float* kbuf   = (float*)(ws + o_k);
    float* vbuf   = (float*)(ws + o_v);
    float* cumA   = (float*)(ws + o_cumA);
    // hend (29.4 MB) lives in the DEAD outy region of d_out (overwritten by
    // out_proj at step 6).  outy = 33.5 MB >= 29.4 MB.
    float* hend   = outy;

    u16*  pw_in   = (u16*)(ws + o_RA);
    u16*  uplanes = (u16*)(ws + o_RA + pw_in_bytes);
    float* xbc    = (float*)(ws + o_RA);
    float* concat = (float*)(ws + o_RA);
    float* sch    = (float*)(ws + o_RA + (size_t)ROWS * DIN * 4);
    float* bufZ   = (float*)(ws + o_RB);
    u16*  pw_out  = (u16*)(ws + o_RB);
    u16*  pw_s1   = (u16*)(ws + o_RB + (size_t)16 * 1024 * 1024);
    float* qbuf   = (float*)(ws + o_RB);
    float* bufX   = (float*)(ws + o_RC);
    float* yscan  = (float*)(ws + o_RC);

    // 0. in_w plane split + fused ssum zero (RA is dead until conv)
    {
        long n = (long)DPROJ * 1024;
        split2_kernel<<<(n + 255) / 256, 256, 0, stream>>>(in_w, pw_in, n, ssum);
    }
    // 1. rmsnorm(x) -> u as 2 fp16 planes (RA, behind pw_in)
    rms_x_kernel<<<ROWS, 256, 0, stream>>>(x, norm_w, uplanes, (long)ROWS * D);
    // 2. in_proj (fp16 2-plane, A+B pre-split DMA): -> bufZ, bufX, dt/dA
    gemm_f32<2, 0, true, true><<<dim3(35, 64), 256, 0, stream>>>(
        nullptr, 0, uplanes, (size_t)ROWS * D,
        nullptr, 0, pw_in, (size_t)DPROJ * 1024,
        ROWS, DPROJ, 1024,
        bufZ, bufX, dt_bias, A_log, dtb, dab);
    // 3. conv + silu (f32, float4 tile load) -> xbc (R_A, over dead planes)
    conv_kernel<<<Bb * 32 * 36, 256, 0, stream>>>(bufX, conv_w, conv_b, xbc);
    // 4. scan v10: NC=8 chunked phase A + boundary prefix + correction
    scan_kernel<<<Bb * NH * NC * 4, 64, 0, stream>>>(xbc, dtb, dab, Dp, yscan, hend, cumA);
    scanfix_kernel<<<128, 256, 0, stream>>>(hend, cumA);
    scancorr_kernel<<<128 * (NC - 1) * (CL / 128), 256, 0, stream>>>(hend, cumA, xbc, yscan);
    // 5. ssm rmsnorm (f32, vectorized, in-place over yscan); bufZ dead after
    ssmnorm_kernel<<<ROWS, 256, 0, stream>>>(yscan, bufZ, ssm_w);
    // 5b. out_w + s_w1 plane splits (one dual launch) into dead R_B
    {
        long n = (long)1024 * 2048;
        long n2 = (long)256 * 1024;
        split2_dual_kernel<<<(int)((n + n2 + 255) / 256), 256, 0, stream>>>(
            out_w, pw_out, n, s_w1, pw_s1, n2);
    }
    // 6. out_proj (fp16 2-plane, DMA B) + residual -> outy, concat (R_A)
    gemm_f32<2, 2, true, false><<<dim3(8, 64), 256, 0, stream>>>(
        yscan, 2048, nullptr, 0,
        nullptr, 0, pw_out, (size_t)1024 * 2048,
        ROWS, 1024, 2048,
        outy, concat, x, nullptr, nullptr, nullptr);
    // 7. score1 (fp16 2-plane, DMA B, relu) -> sch
    gemm_f32<2, 1, true, false><<<dim3(2, 64), 256, 0, stream>>>(
        outy, 1024, nullptr, 0,
        nullptr, 0, pw_s1, (size_t)256 * 1024,
        ROWS, 256, 1024,
        sch, nullptr, nullptr, nullptr, nullptr, nullptr);
    // 8. score2 (f64, float4 loads) -> scores, ssum
    score2_kernel<<<ROWS / 4, 256, 0, stream>>>(sch, s_w2, scores, ssum);
    // 9. top-64 (register-resident shuffle selection)
    top64_kernel<<<Bb, 256, 0, stream>>>(scores, tidx, tval);
    // 10. summaries (float4 loads, f64 accum, order unchanged)
    summ_kernel<<<Bb * 64, 256, 0, stream>>>(outy, tidx, summ_w, summ);
    // 11. pool update -> d_out pool/pri/counts + rmask
    pool_kernel<<<Bb, 256, 0, stream>>>(pool_in, pri_in, cnt_in, tval, summ, ssum,
                                        outpool, outpri, outcnt, rmk);
    // 12. k, v
    kv_kernel<<<Bb * 64, 256, 0, stream>>>(outpool, k_w, v_w, kbuf, vbuf);
    // 13. q = y @ q_w^T (fp16 single-plane); qbuf overlays dead out_w planes
    gemm_f32<1, 3, false, false><<<dim3(2, 64), 256, 0, stream>>>(
        outy, 1024, nullptr, 0,
        q_w, 1024, nullptr, 0,
        ROWS, 256, 1024,
        qbuf, nullptr, nullptr, nullptr, nullptr, nullptr);
    // 14. attention -> retrieved (f32, concat second half)
    attn_kernel<<<ROWS, 256, 0, stream>>>(qbuf, kbuf, vbuf, outcnt, concat);
    // 15. gate GEMM (fp16 single-plane) + final y update
    gemm_f32<1, 4, false, false><<<dim3(8, 64), 256, 0, stream>>>(
        concat, 2048, nullptr, 0,
        gate_w, 2048, nullptr, 0,
        ROWS, 1024, 2048,
        outy, nullptr, concat, rmk, nullptr, nullptr);
}